// Round 7
// baseline (161.106 us; speedup 1.0000x reference)
//
#include <hip/hip_runtime.h>
#include <hip/hip_bf16.h>

// B=2, S=2048, H=16, D=64, D_MODEL=1024, M=B*S=4096
// ws layout (bytes):
//   WT  @ 0MB  : [4][1024][1024] bf16 (w_q^T, w_k^T, w_v^T, w_o^T)  8MB
//   Xb  @ 8MB  : [3][4096][1024] bf16 (q,k,v converted)            24MB
//   Qh  @ 32MB : [32][2048][64]  bf16 (scaled by 0.125*log2e)       8MB
//   Kh  @ 40MB : [32][2048][64]  bf16                               8MB
//   Vt  @ 48MB : [32][64][2048]  bf16 (per-head transposed V)       8MB
//   Ob  @ 56MB : [4096][1024]    bf16 (attention output)            8MB

using bf16x8 = __attribute__((ext_vector_type(8))) short;
using f32x4  = __attribute__((ext_vector_type(4))) float;
using u32x4  = __attribute__((ext_vector_type(4))) unsigned;
typedef unsigned short u16;
using u16x4 = __attribute__((ext_vector_type(4))) u16;
using u16x8 = __attribute__((ext_vector_type(8))) u16;

#define GLDS16(g, l) __builtin_amdgcn_global_load_lds( \
    (const __attribute__((address_space(1))) void*)(g), \
    (__attribute__((address_space(3))) void*)(l), 16, 0, 0)

#if __has_builtin(__builtin_amdgcn_exp2f)
#define EXP2(x) __builtin_amdgcn_exp2f(x)
#else
#define EXP2(x) exp2f(x)
#endif

// Raw s_barrier is IntrNoMem: pair it with compiler memory fences so LDS
// reads/writes cannot be moved across it at compile time.
__device__ __forceinline__ void block_sync() {
  __builtin_amdgcn_sched_barrier(0);
  asm volatile("" ::: "memory");
  __builtin_amdgcn_s_barrier();
  asm volatile("" ::: "memory");
  __builtin_amdgcn_sched_barrier(0);
}

__device__ __forceinline__ u16 f2bf(float f) {
  unsigned u = __builtin_bit_cast(unsigned, f);
  u += 0x7fffu + ((u >> 16) & 1u);
  return (u16)(u >> 16);
}

// packed f32->bf16 RNE (no builtin on gfx950; T12 primitive)
__device__ __forceinline__ unsigned cvt_pk_bf16(float lo, float hi) {
  unsigned r;
  asm("v_cvt_pk_bf16_f32 %0, %1, %2" : "=v"(r) : "v"(lo), "v"(hi));
  return r;
}

__device__ __forceinline__ float fmax3(float a, float b, float c) {
  return fmaxf(fmaxf(a, b), c);  // clang fuses to v_max3_f32
}

// ---------- kernel 1: weight transpose+convert: WT[z][n][k] = bf16(w_z[k][n]) ----------
__global__ __launch_bounds__(256) void wtrans_kernel(
    const float* __restrict__ wq, const float* __restrict__ wk,
    const float* __restrict__ wv, const float* __restrict__ wo,
    u16* __restrict__ dst) {
  __shared__ float t[32][33];
  const int z = blockIdx.z;
  const float* src = (z == 0) ? wq : (z == 1) ? wk : (z == 2) ? wv : wo;
  u16* d = dst + (size_t)z * 1024 * 1024;
  const int tx = threadIdx.x & 31, ty = threadIdx.x >> 5;
  const int bx = blockIdx.x * 32, by = blockIdx.y * 32;
#pragma unroll
  for (int j = 0; j < 4; j++)
    t[ty + j * 8][tx] = src[(size_t)(by + ty + j * 8) * 1024 + bx + tx];
  __syncthreads();
#pragma unroll
  for (int j = 0; j < 4; j++)
    d[(size_t)(bx + ty + j * 8) * 1024 + by + tx] = f2bf(t[tx][ty + j * 8]);
}

// ---------- kernel 2: convert q,k,v fp32 -> bf16 ----------
__global__ __launch_bounds__(256) void cvt_in_kernel(
    const float* __restrict__ q, const float* __restrict__ k,
    const float* __restrict__ v, u16* __restrict__ dst) {
  const int z = blockIdx.y;
  const float* src = (z == 0) ? q : (z == 1) ? k : v;
  u16* d = dst + (size_t)z * 4096 * 1024;
  size_t i = ((size_t)blockIdx.x * 256 + threadIdx.x) * 4;
  float4 f = *(const float4*)(src + i);
  uint2 o2 = make_uint2(cvt_pk_bf16(f.x, f.y), cvt_pk_bf16(f.z, f.w));
  *(uint2*)(d + i) = o2;
}

// ---------- shared GEMM core: 128x128 tile, BK=64, swizzled LDS, global_load_lds ----------
__device__ __forceinline__ void gemm128(const u16* __restrict__ A,
                                        const u16* __restrict__ B,
                                        int arow0, int bcol0,
                                        u16* ldsA, u16* ldsB,
                                        f32x4 acc[4][4]) {
  const int tid = threadIdx.x;
  const int lane = tid & 63, wave = tid >> 6;
  const int lr = lane & 15, lg = lane >> 4;
  const int wr = (wave >> 1) * 64, wc = (wave & 1) * 64;
  for (int kt = 0; kt < 1024; kt += 64) {
#pragma unroll
    for (int i = 0; i < 4; i++) {
      int o = (i * 256 + tid) * 8;
      int row = o >> 6, ch = (o >> 3) & 7;
      int sc = (ch ^ (row & 7)) << 3;  // inverse-swizzled source chunk
      GLDS16(A + (size_t)(arow0 + row) * 1024 + kt + sc, &ldsA[o]);
      GLDS16(B + (size_t)(bcol0 + row) * 1024 + kt + sc, &ldsB[o]);
    }
    __syncthreads();
#pragma unroll
    for (int kk = 0; kk < 2; kk++) {
      bf16x8 af[4], bfr[4];
      const int ke = kk * 32 + lg * 8;
#pragma unroll
      for (int m = 0; m < 4; m++) {
        int row = wr + m * 16 + lr;
        af[m] = *(const bf16x8*)&ldsA[row * 64 + (ke ^ ((row & 7) << 3))];
      }
#pragma unroll
      for (int n = 0; n < 4; n++) {
        int row = wc + n * 16 + lr;
        bfr[n] = *(const bf16x8*)&ldsB[row * 64 + (ke ^ ((row & 7) << 3))];
      }
#pragma unroll
      for (int m = 0; m < 4; m++)
#pragma unroll
        for (int n = 0; n < 4; n++)
          acc[m][n] = __builtin_amdgcn_mfma_f32_16x16x32_bf16(af[m], bfr[n],
                                                              acc[m][n], 0, 0, 0);
    }
    __syncthreads();
  }
}

// ---------- kernel 3: QKV projections ----------
__global__ __launch_bounds__(256) void proj_kernel(
    const u16* __restrict__ Xb, const u16* __restrict__ WT,
    u16* __restrict__ Qh, u16* __restrict__ Kh, u16* __restrict__ Vt) {
  __shared__ u16 lds[16384];
  const int z = blockIdx.z;
  const u16* A = Xb + (size_t)z * 4096 * 1024;
  const u16* B = WT + (size_t)z * 1024 * 1024;
  const int arow0 = blockIdx.y * 128, bcol0 = blockIdx.x * 128;
  f32x4 acc[4][4] = {};
  gemm128(A, B, arow0, bcol0, lds, lds + 8192, acc);

  const int lane = threadIdx.x & 63, wave = threadIdx.x >> 6;
  const int lr = lane & 15, lg = lane >> 4;
  const int wr = (wave >> 1) * 64, wc = (wave & 1) * 64;

  if (z == 2) {
    // V: transpose through LDS -> Vt[(b*16+h)*64+d][s]
    u16* T = lds;  // [128 c][128 s], swizzled rows
#pragma unroll
    for (int m = 0; m < 4; m++)
#pragma unroll
      for (int n = 0; n < 4; n++)
#pragma unroll
        for (int r = 0; r < 4; r++) {
          int sl = wr + m * 16 + lg * 4 + r;
          int cl = wc + n * 16 + lr;
          T[cl * 128 + (sl ^ ((cl & 7) << 3))] = f2bf(acc[m][n][r]);
        }
    __syncthreads();
    const int t = threadIdx.x;
    const int cl = t >> 1, s0 = (t & 1) * 64;
    const int gc = bcol0 + cl;
    const size_t vrow = ((size_t)(arow0 >> 11) * 16 + (gc >> 6)) * 64 + (gc & 63);
#pragma unroll
    for (int j = 0; j < 8; j++) {
      int sl = s0 + j * 8;
      u16x8 vv = *(const u16x8*)&T[cl * 128 + (sl ^ ((cl & 7) << 3))];
      *(u16x8*)&Vt[vrow * 2048 + (size_t)((arow0 & 2047) + sl)] = vv;
    }
  } else {
    const float scale = (z == 0) ? 0.18033688f : 1.0f;  // 0.125 * log2(e)
    u16* dst = (z == 0) ? Qh : Kh;
#pragma unroll
    for (int m = 0; m < 4; m++)
#pragma unroll
      for (int n = 0; n < 4; n++)
#pragma unroll
        for (int r = 0; r < 4; r++) {
          int gr = arow0 + wr + m * 16 + lg * 4 + r;
          int gc = bcol0 + wc + n * 16 + lr;
          size_t idx = (((size_t)(gr >> 11) * 16 + (gc >> 6)) * 2048 +
                        (gr & 2047)) * 64 + (gc & 63);
          dst[idx] = f2bf(acc[m][n][r] * scale);
        }
  }
}

// ---------- kernel 4: flash attention (swapped QK^T, P in registers) ----------
// 1024 blocks (XCD-swizzled), 4 waves/block, 16 q-rows per wave. LDS = 48KB
// (triple-buffered K/V -> stage 2 tiles ahead, steady-state vmcnt(8)).
// S^T = mfma(K-frag, Q-frag): lane owns q = lane&15; K rows fed through
// permutation κ(n,a)=32(n>>1)+8(a>>2)+4(n&1)+(a&3) so the lane's 16 keys are
// exactly the PV A-fragment sets {8*lg..+7} u {32+8*lg..+7} -> zero exchange.
// K bank swizzle h(kr)=(kr&3)|(((kr>>3)&1)<<2): bijective on bank-groups for
// every 8 consecutive lanes.
__global__ __launch_bounds__(256, 3) void attn_kernel(
    const u16* __restrict__ Qh, const u16* __restrict__ Kh,
    const u16* __restrict__ Vt, u16* __restrict__ Ob) {
  __shared__ u16 kt[3][64 * 64];  // K tile [key][d], h-swizzled rows
  __shared__ u16 vt[3][64 * 64];  // V^T tile [d][s], xor-swizzled rows
  const int tid = threadIdx.x;
  const int lane = tid & 63, wave = tid >> 6;
  const int lr = lane & 15, lg = lane >> 4;
  // bijective XCD swizzle (1024 % 8 == 0): each XCD owns 4 complete bh's
  const int id = blockIdx.x;
  const int swz = (id & 7) * 128 + (id >> 3);
  const int bh = swz >> 5;
  const int q0 = (swz & 31) * 64;
  const u16* Qb = Qh + ((size_t)bh * 2048 + q0) * 64;
  const u16* Kb = Kh + (size_t)bh * 2048 * 64;
  const u16* Vb = Vt + (size_t)bh * 64 * 2048;

  // Q fragment (B-operand of swapped QK^T)
  bf16x8 aq[2];
#pragma unroll
  for (int kk = 0; kk < 2; kk++)
    aq[kk] = *(const bf16x8*)(Qb + (wave * 16 + lr) * 64 + kk * 32 + lg * 8);

  // K A-operand LDS offsets: perm κ, swizzle h (h depends only on lr)
  const int hsw = (lr & 3) | (((lr >> 2) & 1) << 2);
  int koff[2][4];
#pragma unroll
  for (int n = 0; n < 4; n++) {
    int kr = 32 * (n >> 1) + 8 * (lr >> 2) + 4 * (n & 1) + (lr & 3);
#pragma unroll
    for (int kk = 0; kk < 2; kk++)
      koff[kk][n] = kr * 64 + ((kk * 32 + lg * 8) ^ (hsw << 3));
  }
  // V B-operand LDS offsets
  int voff[2][4];
#pragma unroll
  for (int n = 0; n < 4; n++) {
    int d = n * 16 + lr;
#pragma unroll
    for (int ks = 0; ks < 2; ks++)
      voff[ks][n] = d * 64 + ((ks * 32 + lg * 8) ^ ((d & 7) << 3));
  }

  // hoisted staging addresses (per-lane, loop adds constant strides)
  const int o0 = tid * 8, o1 = (256 + tid) * 8;
  const u16* kg[2];
  const u16* vg[2];
#pragma unroll
  for (int i = 0; i < 2; i++) {
    int o = (i * 256 + tid) * 8;
    int row = o >> 6, ch = (o >> 3) & 7;
    int hk = (row & 3) | (((row >> 3) & 1) << 2);
    kg[i] = Kb + (size_t)row * 64 + ((ch ^ hk) << 3);
    vg[i] = Vb + (size_t)row * 2048 + ((ch ^ (row & 7)) << 3);
  }

  f32x4 oacc[4] = {};
  float mrun = -1e30f, lrun = 0.f;

  auto STAGE = [&](int t, int b) {  // b must be a literal at call site
    u16* kd = &kt[0][0] + b * 4096;
    u16* vd = &vt[0][0] + b * 4096;
    GLDS16(kg[0] + (size_t)t * 4096, kd + o0);
    GLDS16(vg[0] + t * 64, vd + o0);
    GLDS16(kg[1] + (size_t)t * 4096, kd + o1);
    GLDS16(vg[1] + t * 64, vd + o1);
  };

  auto COMPUTE = [&](int cur) {  // cur literal at call site
    // S^T tile: sacc[n][r] = S[key κ(n, lg*4+r)][q=lr] (log2 domain)
    f32x4 sacc[4] = {};
    __builtin_amdgcn_s_setprio(1);
#pragma unroll
    for (int kk = 0; kk < 2; kk++) {
#pragma unroll
      for (int n = 0; n < 4; n++) {
        bf16x8 ka = *(const bf16x8*)&kt[cur][koff[kk][n]];
        sacc[n] = __builtin_amdgcn_mfma_f32_16x16x32_bf16(ka, aq[kk],
                                                          sacc[n], 0, 0, 0);
      }
    }
    __builtin_amdgcn_s_setprio(0);
    // row max: 7 max3 + 1 fmax in-lane, then 2 cross-lane steps
    float t0 = fmax3(sacc[0][0], sacc[0][1], sacc[0][2]);
    float t1 = fmax3(sacc[0][3], sacc[1][0], sacc[1][1]);
    float t2 = fmax3(sacc[1][2], sacc[1][3], sacc[2][0]);
    float t3 = fmax3(sacc[2][1], sacc[2][2], sacc[2][3]);
    float t4 = fmax3(sacc[3][0], sacc[3][1], sacc[3][2]);
    float mx = fmaxf(fmax3(t0, t1, t2), fmax3(t3, t4, sacc[3][3]));
    mx = fmaxf(mx, __shfl_xor(mx, 16));
    mx = fmaxf(mx, __shfl_xor(mx, 32));
    float mnew = fmaxf(mrun, mx);
    // defer-max (T13): skip rescale when growth <= 8 (log2 domain -> p <= 256)
    if (__all(mx - mrun <= 8.0f)) {
      mnew = mrun;
    } else {
      float corr = EXP2(mrun - mnew);
      mrun = mnew;
      lrun *= corr;
      float cr[4];
#pragma unroll
      for (int r = 0; r < 4; r++) cr[r] = __shfl(corr, lg * 4 + r);
#pragma unroll
      for (int n = 0; n < 4; n++)
#pragma unroll
        for (int r = 0; r < 4; r++) oacc[n][r] *= cr[r];
    }
    // p = exp2(s - m), in place; row-sum
    float psum = 0.f;
#pragma unroll
    for (int n = 0; n < 4; n++)
#pragma unroll
      for (int r = 0; r < 4; r++) {
        float p = EXP2(sacc[n][r] - mnew);
        sacc[n][r] = p;
        psum += p;
      }
    psum += __shfl_xor(psum, 16);
    psum += __shfl_xor(psum, 32);
    lrun += psum;
    // pack P into PV A-fragments via v_cvt_pk_bf16_f32
    u32x4 w0 = {cvt_pk_bf16(sacc[0][0], sacc[0][1]),
                cvt_pk_bf16(sacc[0][2], sacc[0][3]),
                cvt_pk_bf16(sacc[1][0], sacc[1][1]),
                cvt_pk_bf16(sacc[1][2], sacc[1][3])};
    u32x4 w1 = {cvt_pk_bf16(sacc[2][0], sacc[2][1]),
                cvt_pk_bf16(sacc[2][2], sacc[2][3]),
                cvt_pk_bf16(sacc[3][0], sacc[3][1]),
                cvt_pk_bf16(sacc[3][2], sacc[3][3])};
    bf16x8 pa0 = __builtin_bit_cast(bf16x8, w0);
    bf16x8 pa1 = __builtin_bit_cast(bf16x8, w1);
    // O += P V
    __builtin_amdgcn_s_setprio(1);
#pragma unroll
    for (int ks = 0; ks < 2; ks++) {
      bf16x8 ap = ks ? pa1 : pa0;
      bf16x8 bv[4];
#pragma unroll
      for (int n = 0; n < 4; n++)
        bv[n] = *(const bf16x8*)&vt[cur][voff[ks][n]];
#pragma unroll
      for (int n = 0; n < 4; n++)
        oacc[n] = __builtin_amdgcn_mfma_f32_16x16x32_bf16(ap, bv[n],
                                                          oacc[n], 0, 0, 0);
    }
    __builtin_amdgcn_s_setprio(0);
  };

#define VMC8 asm volatile("s_waitcnt vmcnt(8)" ::: "memory")
#define VMC4 asm volatile("s_waitcnt vmcnt(4)" ::: "memory")
#define VMC0 asm volatile("s_waitcnt vmcnt(0)" ::: "memory")
  STAGE(0, 0);
  STAGE(1, 1);
  // triple-buffered, 2 tiles in flight; unrolled x3 so buf indices are literals
  for (int t = 0; t < 30; t += 3) {
    STAGE(t + 2, 2); VMC8; block_sync(); COMPUTE(0); block_sync();
    STAGE(t + 3, 0); VMC8; block_sync(); COMPUTE(1); block_sync();
    STAGE(t + 4, 1); VMC8; block_sync(); COMPUTE(2); block_sync();
  }
  // tiles 30 (buf 0) and 31 (buf 1) already staged by the last loop block
  VMC4; block_sync(); COMPUTE(0); block_sync();
  VMC0; block_sync(); COMPUTE(1);
#undef VMC8
#undef VMC4
#undef VMC0

  // epilogue: normalize (inv lives at q=lr; oacc rows are q=lg*4+r)
  const int b = bh >> 4, h = bh & 15;
  float inv = 1.0f / lrun;
  float ivr[4];
#pragma unroll
  for (int r = 0; r < 4; r++) ivr[r] = __shfl(inv, lg * 4 + r);
#pragma unroll
  for (int r = 0; r < 4; r++) {
    int qrow = q0 + wave * 16 + lg * 4 + r;
#pragma unroll
    for (int n = 0; n < 4; n++) {
      int d = n * 16 + lr;
      Ob[((size_t)b * 2048 + qrow) * 1024 + h * 64 + d] = f2bf(oacc[n][r] * ivr[r]);
    }
  }
}

// ---------- kernel 5: output projection -> fp32 d_out ----------
__global__ __launch_bounds__(256) void outproj_kernel(
    const u16* __restrict__ Ob, const u16* __restrict__ WoT,
    float* __restrict__ out) {
  __shared__ u16 lds[16384];
  const int arow0 = blockIdx.y * 128, bcol0 = blockIdx.x * 128;
  f32x4 acc[4][4] = {};
  gemm128(Ob, WoT, arow0, bcol0, lds, lds + 8192, acc);
  const int lane = threadIdx.x & 63, wave = threadIdx.x >> 6;
  const int lr = lane & 15, lg = lane >> 4;
  const int wr = (wave >> 1) * 64, wc = (wave & 1) * 64;
#pragma unroll
  for (int m = 0; m < 4; m++)
#pragma unroll
    for (int n = 0; n < 4; n++)
#pragma unroll
      for (int r = 0; r < 4; r++) {
        int gr = arow0 + wr + m * 16 + lg * 4 + r;
        int gc = bcol0 + wc + n * 16 + lr;
        out[(size_t)gr * 1024 + gc] = acc[m][n][r];
      }
}

extern "C" void kernel_launch(void* const* d_in, const int* in_sizes, int n_in,
                              void* d_out, int out_size, void* d_ws, size_t ws_size,
                              hipStream_t stream) {
  const float* q  = (const float*)d_in[0];
  const float* k  = (const float*)d_in[1];
  const float* v  = (const float*)d_in[2];
  const float* wq = (const float*)d_in[3];
  const float* wk = (const float*)d_in[4];
  const float* wv = (const float*)d_in[5];
  const float* wo = (const float*)d_in[6];
  float* out = (float*)d_out;
  char* ws = (char*)d_ws;

  u16* WT = (u16*)ws;                                    // [4][1024][1024]
  u16* Xb = (u16*)(ws + (size_t)8  * 1024 * 1024);       // [3][4096][1024]
  u16* Qh = (u16*)(ws + (size_t)32 * 1024 * 1024);       // [32][2048][64]
  u16* Kh = (u16*)(ws + (size_t)40 * 1024 * 1024);       // [32][2048][64]
  u16* Vt = (u16*)(ws + (size_t)48 * 1024 * 1024);       // [32][64][2048]
  u16* Ob = (u16*)(ws + (size_t)56 * 1024 * 1024);       // [4096][1024]

  wtrans_kernel<<<dim3(32, 32, 4), 256, 0, stream>>>(wq, wk, wv, wo, WT);
  cvt_in_kernel<<<dim3(4096, 3), 256, 0, stream>>>(q, k, v, Xb);
  proj_kernel<<<dim3(8, 32, 3), 256, 0, stream>>>(Xb, WT, Qh, Kh, Vt);
  attn_kernel<<<dim3(1024), 256, 0, stream>>>(Qh, Kh, Vt, Ob);
  outproj_kernel<<<dim3(8, 32), 256, 0, stream>>>(Ob, WT + (size_t)3 * 1024 * 1024, out);
}

// Round 8
// 137.512 us; speedup vs baseline: 1.1716x; 1.1716x over previous
//
#include <hip/hip_runtime.h>
#include <hip/hip_bf16.h>

// B=2, S=2048, H=16, D=64, D_MODEL=1024, M=B*S=4096
// ws layout (bytes):
//   WT  @ 0MB  : [4][1024][1024] bf16 (w_q^T, w_k^T, w_v^T, w_o^T)  8MB
//   Xb  @ 8MB  : [3][4096][1024] bf16 (q,k,v converted)            24MB
//   Qh  @ 32MB : [32][2048][64]  bf16 (scaled by 0.125*log2e)       8MB
//   Kh  @ 40MB : [32][2048][64]  bf16                               8MB
//   Vt  @ 48MB : [32][64][2048]  bf16 (per-head transposed V)       8MB
//   Ob  @ 56MB : [4096][1024]    bf16 (attention output)            8MB

using bf16x8 = __attribute__((ext_vector_type(8))) short;
using f32x4  = __attribute__((ext_vector_type(4))) float;
using u32x4  = __attribute__((ext_vector_type(4))) unsigned;
typedef unsigned short u16;
using u16x4 = __attribute__((ext_vector_type(4))) u16;
using u16x8 = __attribute__((ext_vector_type(8))) u16;

#define GLDS16(g, l) __builtin_amdgcn_global_load_lds( \
    (const __attribute__((address_space(1))) void*)(g), \
    (__attribute__((address_space(3))) void*)(l), 16, 0, 0)

#if __has_builtin(__builtin_amdgcn_exp2f)
#define EXP2(x) __builtin_amdgcn_exp2f(x)
#else
#define EXP2(x) exp2f(x)
#endif

// Raw s_barrier is IntrNoMem: pair it with compiler memory fences so LDS
// reads/writes cannot be moved across it at compile time.
__device__ __forceinline__ void block_sync() {
  __builtin_amdgcn_sched_barrier(0);
  asm volatile("" ::: "memory");
  __builtin_amdgcn_s_barrier();
  asm volatile("" ::: "memory");
  __builtin_amdgcn_sched_barrier(0);
}

__device__ __forceinline__ u16 f2bf(float f) {
  unsigned u = __builtin_bit_cast(unsigned, f);
  u += 0x7fffu + ((u >> 16) & 1u);
  return (u16)(u >> 16);
}

// packed f32->bf16 RNE (no builtin on gfx950; T12 primitive)
__device__ __forceinline__ unsigned cvt_pk_bf16(float lo, float hi) {
  unsigned r;
  asm("v_cvt_pk_bf16_f32 %0, %1, %2" : "=v"(r) : "v"(lo), "v"(hi));
  return r;
}

__device__ __forceinline__ float fmax3(float a, float b, float c) {
  return fmaxf(fmaxf(a, b), c);  // clang fuses to v_max3_f32
}

// ---------- kernel 1: weight transpose+convert: WT[z][n][k] = bf16(w_z[k][n]) ----------
__global__ __launch_bounds__(256) void wtrans_kernel(
    const float* __restrict__ wq, const float* __restrict__ wk,
    const float* __restrict__ wv, const float* __restrict__ wo,
    u16* __restrict__ dst) {
  __shared__ float t[32][33];
  const int z = blockIdx.z;
  const float* src = (z == 0) ? wq : (z == 1) ? wk : (z == 2) ? wv : wo;
  u16* d = dst + (size_t)z * 1024 * 1024;
  const int tx = threadIdx.x & 31, ty = threadIdx.x >> 5;
  const int bx = blockIdx.x * 32, by = blockIdx.y * 32;
#pragma unroll
  for (int j = 0; j < 4; j++)
    t[ty + j * 8][tx] = src[(size_t)(by + ty + j * 8) * 1024 + bx + tx];
  __syncthreads();
#pragma unroll
  for (int j = 0; j < 4; j++)
    d[(size_t)(bx + ty + j * 8) * 1024 + by + tx] = f2bf(t[tx][ty + j * 8]);
}

// ---------- kernel 2: convert q,k,v fp32 -> bf16 ----------
__global__ __launch_bounds__(256) void cvt_in_kernel(
    const float* __restrict__ q, const float* __restrict__ k,
    const float* __restrict__ v, u16* __restrict__ dst) {
  const int z = blockIdx.y;
  const float* src = (z == 0) ? q : (z == 1) ? k : v;
  u16* d = dst + (size_t)z * 4096 * 1024;
  size_t i = ((size_t)blockIdx.x * 256 + threadIdx.x) * 4;
  float4 f = *(const float4*)(src + i);
  uint2 o2 = make_uint2(cvt_pk_bf16(f.x, f.y), cvt_pk_bf16(f.z, f.w));
  *(uint2*)(d + i) = o2;
}

// ---------- shared GEMM core: 128x128 tile, BK=64, swizzled LDS, global_load_lds ----------
__device__ __forceinline__ void gemm128(const u16* __restrict__ A,
                                        const u16* __restrict__ B,
                                        int arow0, int bcol0,
                                        u16* ldsA, u16* ldsB,
                                        f32x4 acc[4][4]) {
  const int tid = threadIdx.x;
  const int lane = tid & 63, wave = tid >> 6;
  const int lr = lane & 15, lg = lane >> 4;
  const int wr = (wave >> 1) * 64, wc = (wave & 1) * 64;
  for (int kt = 0; kt < 1024; kt += 64) {
#pragma unroll
    for (int i = 0; i < 4; i++) {
      int o = (i * 256 + tid) * 8;
      int row = o >> 6, ch = (o >> 3) & 7;
      int sc = (ch ^ (row & 7)) << 3;  // inverse-swizzled source chunk
      GLDS16(A + (size_t)(arow0 + row) * 1024 + kt + sc, &ldsA[o]);
      GLDS16(B + (size_t)(bcol0 + row) * 1024 + kt + sc, &ldsB[o]);
    }
    __syncthreads();
#pragma unroll
    for (int kk = 0; kk < 2; kk++) {
      bf16x8 af[4], bfr[4];
      const int ke = kk * 32 + lg * 8;
#pragma unroll
      for (int m = 0; m < 4; m++) {
        int row = wr + m * 16 + lr;
        af[m] = *(const bf16x8*)&ldsA[row * 64 + (ke ^ ((row & 7) << 3))];
      }
#pragma unroll
      for (int n = 0; n < 4; n++) {
        int row = wc + n * 16 + lr;
        bfr[n] = *(const bf16x8*)&ldsB[row * 64 + (ke ^ ((row & 7) << 3))];
      }
#pragma unroll
      for (int m = 0; m < 4; m++)
#pragma unroll
        for (int n = 0; n < 4; n++)
          acc[m][n] = __builtin_amdgcn_mfma_f32_16x16x32_bf16(af[m], bfr[n],
                                                              acc[m][n], 0, 0, 0);
    }
    __syncthreads();
  }
}

// ---------- kernel 3: QKV projections ----------
__global__ __launch_bounds__(256) void proj_kernel(
    const u16* __restrict__ Xb, const u16* __restrict__ WT,
    u16* __restrict__ Qh, u16* __restrict__ Kh, u16* __restrict__ Vt) {
  __shared__ u16 lds[16384];
  const int z = blockIdx.z;
  const u16* A = Xb + (size_t)z * 4096 * 1024;
  const u16* B = WT + (size_t)z * 1024 * 1024;
  const int arow0 = blockIdx.y * 128, bcol0 = blockIdx.x * 128;
  f32x4 acc[4][4] = {};
  gemm128(A, B, arow0, bcol0, lds, lds + 8192, acc);

  const int lane = threadIdx.x & 63, wave = threadIdx.x >> 6;
  const int lr = lane & 15, lg = lane >> 4;
  const int wr = (wave >> 1) * 64, wc = (wave & 1) * 64;

  if (z == 2) {
    // V: transpose through LDS -> Vt[(b*16+h)*64+d][s]
    u16* T = lds;  // [128 c][128 s], swizzled rows
#pragma unroll
    for (int m = 0; m < 4; m++)
#pragma unroll
      for (int n = 0; n < 4; n++)
#pragma unroll
        for (int r = 0; r < 4; r++) {
          int sl = wr + m * 16 + lg * 4 + r;
          int cl = wc + n * 16 + lr;
          T[cl * 128 + (sl ^ ((cl & 7) << 3))] = f2bf(acc[m][n][r]);
        }
    __syncthreads();
    const int t = threadIdx.x;
    const int cl = t >> 1, s0 = (t & 1) * 64;
    const int gc = bcol0 + cl;
    const size_t vrow = ((size_t)(arow0 >> 11) * 16 + (gc >> 6)) * 64 + (gc & 63);
#pragma unroll
    for (int j = 0; j < 8; j++) {
      int sl = s0 + j * 8;
      u16x8 vv = *(const u16x8*)&T[cl * 128 + (sl ^ ((cl & 7) << 3))];
      *(u16x8*)&Vt[vrow * 2048 + (size_t)((arow0 & 2047) + sl)] = vv;
    }
  } else {
    const float scale = (z == 0) ? 0.18033688f : 1.0f;  // 0.125 * log2(e)
    u16* dst = (z == 0) ? Qh : Kh;
#pragma unroll
    for (int m = 0; m < 4; m++)
#pragma unroll
      for (int n = 0; n < 4; n++)
#pragma unroll
        for (int r = 0; r < 4; r++) {
          int gr = arow0 + wr + m * 16 + lg * 4 + r;
          int gc = bcol0 + wc + n * 16 + lr;
          size_t idx = (((size_t)(gr >> 11) * 16 + (gc >> 6)) * 2048 +
                        (gr & 2047)) * 64 + (gc & 63);
          dst[idx] = f2bf(acc[m][n][r] * scale);
        }
  }
}

// ---------- kernel 4: flash attention (swapped QK^T, P in registers) ----------
// 1024 blocks (XCD-swizzled), 4 waves/block, 16 q-rows per wave. LDS = 32KB
// -> 4 blocks/CU, grid exactly all-resident (R7 lesson: occupancy > depth).
// S^T = mfma(K-frag, Q-frag): lane owns q = lane&15; K rows fed through
// permutation κ(n,a)=32(n>>1)+8(a>>2)+4(n&1)+(a&3) so the lane's 16 keys are
// exactly the PV A-fragment sets {8*lg..+7} u {32+8*lg..+7} -> zero exchange.
// K bank swizzle h(kr)=(kr&3)|(((kr>>3)&1)<<2): bijective on bank-groups for
// every 8 consecutive lanes.
__global__ __launch_bounds__(256, 4) void attn_kernel(
    const u16* __restrict__ Qh, const u16* __restrict__ Kh,
    const u16* __restrict__ Vt, u16* __restrict__ Ob) {
  __shared__ u16 kt[2][64 * 64];  // K tile [key][d], h-swizzled rows
  __shared__ u16 vt[2][64 * 64];  // V^T tile [d][s], xor-swizzled rows
  const int tid = threadIdx.x;
  const int lane = tid & 63, wave = tid >> 6;
  const int lr = lane & 15, lg = lane >> 4;
  // bijective XCD swizzle (1024 % 8 == 0): each XCD owns 4 complete bh's
  // -> K/V working set 2MB per XCD L2 (FETCH_SIZE 69.7 -> 12.3MB, R7-proven)
  const int id = blockIdx.x;
  const int swz = (id & 7) * 128 + (id >> 3);
  const int bh = swz >> 5;
  const int q0 = (swz & 31) * 64;
  const u16* Qb = Qh + ((size_t)bh * 2048 + q0) * 64;
  const u16* Kb = Kh + (size_t)bh * 2048 * 64;
  const u16* Vb = Vt + (size_t)bh * 64 * 2048;

  // Q fragment (B-operand of swapped QK^T)
  bf16x8 aq[2];
#pragma unroll
  for (int kk = 0; kk < 2; kk++)
    aq[kk] = *(const bf16x8*)(Qb + (wave * 16 + lr) * 64 + kk * 32 + lg * 8);

  // K A-operand LDS offsets: perm κ, swizzle h (h depends only on lr)
  const int hsw = (lr & 3) | (((lr >> 2) & 1) << 2);
  int koff[2][4];
#pragma unroll
  for (int n = 0; n < 4; n++) {
    int kr = 32 * (n >> 1) + 8 * (lr >> 2) + 4 * (n & 1) + (lr & 3);
#pragma unroll
    for (int kk = 0; kk < 2; kk++)
      koff[kk][n] = kr * 64 + ((kk * 32 + lg * 8) ^ (hsw << 3));
  }
  // V B-operand LDS offsets
  int voff[2][4];
#pragma unroll
  for (int n = 0; n < 4; n++) {
    int d = n * 16 + lr;
#pragma unroll
    for (int ks = 0; ks < 2; ks++)
      voff[ks][n] = d * 64 + ((ks * 32 + lg * 8) ^ ((d & 7) << 3));
  }

  // hoisted staging addresses (per-lane, loop adds constant strides)
  const int o0 = tid * 8, o1 = (256 + tid) * 8;
  const u16* kg[2];
  const u16* vg[2];
#pragma unroll
  for (int i = 0; i < 2; i++) {
    int o = (i * 256 + tid) * 8;
    int row = o >> 6, ch = (o >> 3) & 7;
    int hk = (row & 3) | (((row >> 3) & 1) << 2);
    kg[i] = Kb + (size_t)row * 64 + ((ch ^ hk) << 3);
    vg[i] = Vb + (size_t)row * 2048 + ((ch ^ (row & 7)) << 3);
  }

  f32x4 oacc[4] = {};
  float mrun = -1e30f, lrun = 0.f;

  auto STAGE = [&](int t, int b) {  // b must be a literal at call site
    u16* kd = &kt[0][0] + b * 4096;
    u16* vd = &vt[0][0] + b * 4096;
    GLDS16(kg[0] + (size_t)t * 4096, kd + o0);
    GLDS16(vg[0] + t * 64, vd + o0);
    GLDS16(kg[1] + (size_t)t * 4096, kd + o1);
    GLDS16(vg[1] + t * 64, vd + o1);
  };

  auto COMPUTE = [&](int cur) {  // cur literal at call site
    // S^T tile: sacc[n][r] = S[key κ(n, lg*4+r)][q=lr] (log2 domain)
    f32x4 sacc[4] = {};
#pragma unroll
    for (int kk = 0; kk < 2; kk++) {
#pragma unroll
      for (int n = 0; n < 4; n++) {
        bf16x8 ka = *(const bf16x8*)&kt[cur][koff[kk][n]];
        sacc[n] = __builtin_amdgcn_mfma_f32_16x16x32_bf16(ka, aq[kk],
                                                          sacc[n], 0, 0, 0);
      }
    }
    // row max: 7 max3 + 1 fmax in-lane, then 2 cross-lane steps
    float t0 = fmax3(sacc[0][0], sacc[0][1], sacc[0][2]);
    float t1 = fmax3(sacc[0][3], sacc[1][0], sacc[1][1]);
    float t2 = fmax3(sacc[1][2], sacc[1][3], sacc[2][0]);
    float t3 = fmax3(sacc[2][1], sacc[2][2], sacc[2][3]);
    float t4 = fmax3(sacc[3][0], sacc[3][1], sacc[3][2]);
    float mx = fmaxf(fmax3(t0, t1, t2), fmax3(t3, t4, sacc[3][3]));
    mx = fmaxf(mx, __shfl_xor(mx, 16));
    mx = fmaxf(mx, __shfl_xor(mx, 32));
    float mnew = fmaxf(mrun, mx);
    // defer-max (T13): skip rescale when growth <= 8 (log2 domain -> p <= 256)
    if (__all(mx - mrun <= 8.0f)) {
      mnew = mrun;
    } else {
      float corr = EXP2(mrun - mnew);
      mrun = mnew;
      lrun *= corr;
      float cr[4];
#pragma unroll
      for (int r = 0; r < 4; r++) cr[r] = __shfl(corr, lg * 4 + r);
#pragma unroll
      for (int n = 0; n < 4; n++)
#pragma unroll
        for (int r = 0; r < 4; r++) oacc[n][r] *= cr[r];
    }
    // p = exp2(s - m), in place; row-sum
    float psum = 0.f;
#pragma unroll
    for (int n = 0; n < 4; n++)
#pragma unroll
      for (int r = 0; r < 4; r++) {
        float p = EXP2(sacc[n][r] - mnew);
        sacc[n][r] = p;
        psum += p;
      }
    psum += __shfl_xor(psum, 16);
    psum += __shfl_xor(psum, 32);
    lrun += psum;
    // pack P into PV A-fragments via v_cvt_pk_bf16_f32
    u32x4 w0 = {cvt_pk_bf16(sacc[0][0], sacc[0][1]),
                cvt_pk_bf16(sacc[0][2], sacc[0][3]),
                cvt_pk_bf16(sacc[1][0], sacc[1][1]),
                cvt_pk_bf16(sacc[1][2], sacc[1][3])};
    u32x4 w1 = {cvt_pk_bf16(sacc[2][0], sacc[2][1]),
                cvt_pk_bf16(sacc[2][2], sacc[2][3]),
                cvt_pk_bf16(sacc[3][0], sacc[3][1]),
                cvt_pk_bf16(sacc[3][2], sacc[3][3])};
    bf16x8 pa0 = __builtin_bit_cast(bf16x8, w0);
    bf16x8 pa1 = __builtin_bit_cast(bf16x8, w1);
    // O += P V
#pragma unroll
    for (int ks = 0; ks < 2; ks++) {
      bf16x8 ap = ks ? pa1 : pa0;
      bf16x8 bv[4];
#pragma unroll
      for (int n = 0; n < 4; n++)
        bv[n] = *(const bf16x8*)&vt[cur][voff[ks][n]];
#pragma unroll
      for (int n = 0; n < 4; n++)
        oacc[n] = __builtin_amdgcn_mfma_f32_16x16x32_bf16(ap, bv[n],
                                                          oacc[n], 0, 0, 0);
    }
  };

#define VMC4 asm volatile("s_waitcnt vmcnt(4)" ::: "memory")
  STAGE(0, 0);
  // unrolled x2 so buffer indices are compile-time (ds offsets -> immediates)
  for (int t = 0; t < 30; t += 2) {
    STAGE(t + 1, 1); VMC4; block_sync();
    COMPUTE(0); block_sync();
    STAGE(t + 2, 0); VMC4; block_sync();
    COMPUTE(1); block_sync();
  }
  STAGE(31, 1); VMC4; block_sync();
  COMPUTE(0); block_sync();
  asm volatile("s_waitcnt vmcnt(0)" ::: "memory");
  block_sync();
  COMPUTE(1);
#undef VMC4

  // epilogue: normalize (inv lives at q=lr; oacc rows are q=lg*4+r)
  const int b = bh >> 4, h = bh & 15;
  float inv = 1.0f / lrun;
  float ivr[4];
#pragma unroll
  for (int r = 0; r < 4; r++) ivr[r] = __shfl(inv, lg * 4 + r);
#pragma unroll
  for (int r = 0; r < 4; r++) {
    int qrow = q0 + wave * 16 + lg * 4 + r;
#pragma unroll
    for (int n = 0; n < 4; n++) {
      int d = n * 16 + lr;
      Ob[((size_t)b * 2048 + qrow) * 1024 + h * 64 + d] = f2bf(oacc[n][r] * ivr[r]);
    }
  }
}

// ---------- kernel 5: output projection (128x64 tile -> 512 blocks, 2/CU) ----------
__global__ __launch_bounds__(256) void outproj_kernel(
    const u16* __restrict__ Ob, const u16* __restrict__ WoT,
    float* __restrict__ out) {
  __shared__ u16 ldsA[128 * 64];  // 16KB, swizzled rows
  __shared__ u16 ldsB[64 * 64];   //  8KB, swizzled rows
  const int tid = threadIdx.x;
  const int lane = tid & 63, wave = tid >> 6;
  const int lr = lane & 15, lg = lane >> 4;
  const int wr = (wave >> 1) * 64;  // M offset (0/64)
  const int wc = (wave & 1) * 32;   // N offset (0/32)
  const int arow0 = blockIdx.y * 128, bcol0 = blockIdx.x * 64;
  f32x4 acc[4][2] = {};
  for (int kt = 0; kt < 1024; kt += 64) {
#pragma unroll
    for (int i = 0; i < 4; i++) {
      int o = (i * 256 + tid) * 8;
      int row = o >> 6, ch = (o >> 3) & 7;
      int sc = (ch ^ (row & 7)) << 3;
      GLDS16(Ob + (size_t)(arow0 + row) * 1024 + kt + sc, &ldsA[o]);
    }
#pragma unroll
    for (int i = 0; i < 2; i++) {
      int o = (i * 256 + tid) * 8;
      int row = o >> 6, ch = (o >> 3) & 7;
      int sc = (ch ^ (row & 7)) << 3;
      GLDS16(WoT + (size_t)(bcol0 + row) * 1024 + kt + sc, &ldsB[o]);
    }
    __syncthreads();
#pragma unroll
    for (int kk = 0; kk < 2; kk++) {
      const int ke = kk * 32 + lg * 8;
      bf16x8 af[4], bfr[2];
#pragma unroll
      for (int m = 0; m < 4; m++) {
        int row = wr + m * 16 + lr;
        af[m] = *(const bf16x8*)&ldsA[row * 64 + (ke ^ ((row & 7) << 3))];
      }
#pragma unroll
      for (int n = 0; n < 2; n++) {
        int row = wc + n * 16 + lr;
        bfr[n] = *(const bf16x8*)&ldsB[row * 64 + (ke ^ ((row & 7) << 3))];
      }
#pragma unroll
      for (int m = 0; m < 4; m++)
#pragma unroll
        for (int n = 0; n < 2; n++)
          acc[m][n] = __builtin_amdgcn_mfma_f32_16x16x32_bf16(af[m], bfr[n],
                                                              acc[m][n], 0, 0, 0);
    }
    __syncthreads();
  }
#pragma unroll
  for (int m = 0; m < 4; m++)
#pragma unroll
    for (int n = 0; n < 2; n++)
#pragma unroll
      for (int r = 0; r < 4; r++) {
        int gr = arow0 + wr + m * 16 + lg * 4 + r;
        int gc = bcol0 + wc + n * 16 + lr;
        out[(size_t)gr * 1024 + gc] = acc[m][n][r];
      }
}

extern "C" void kernel_launch(void* const* d_in, const int* in_sizes, int n_in,
                              void* d_out, int out_size, void* d_ws, size_t ws_size,
                              hipStream_t stream) {
  const float* q  = (const float*)d_in[0];
  const float* k  = (const float*)d_in[1];
  const float* v  = (const float*)d_in[2];
  const float* wq = (const float*)d_in[3];
  const float* wk = (const float*)d_in[4];
  const float* wv = (const float*)d_in[5];
  const float* wo = (const float*)d_in[6];
  float* out = (float*)d_out;
  char* ws = (char*)d_ws;

  u16* WT = (u16*)ws;                                    // [4][1024][1024]
  u16* Xb = (u16*)(ws + (size_t)8  * 1024 * 1024);       // [3][4096][1024]
  u16* Qh = (u16*)(ws + (size_t)32 * 1024 * 1024);       // [32][2048][64]
  u16* Kh = (u16*)(ws + (size_t)40 * 1024 * 1024);       // [32][2048][64]
  u16* Vt = (u16*)(ws + (size_t)48 * 1024 * 1024);       // [32][64][2048]
  u16* Ob = (u16*)(ws + (size_t)56 * 1024 * 1024);       // [4096][1024]

  wtrans_kernel<<<dim3(32, 32, 4), 256, 0, stream>>>(wq, wk, wv, wo, WT);
  cvt_in_kernel<<<dim3(4096, 3), 256, 0, stream>>>(q, k, v, Xb);
  proj_kernel<<<dim3(8, 32, 3), 256, 0, stream>>>(Xb, WT, Qh, Kh, Vt);
  attn_kernel<<<dim3(1024), 256, 0, stream>>>(Qh, Kh, Vt, Ob);
  outproj_kernel<<<dim3(16, 32), 256, 0, stream>>>(Ob, WT + (size_t)3 * 1024 * 1024, out);
}

// Round 9
// 132.651 us; speedup vs baseline: 1.2145x; 1.0366x over previous
//
#include <hip/hip_runtime.h>
#include <hip/hip_bf16.h>

// B=2, S=2048, H=16, D=64, D_MODEL=1024, M=B*S=4096
// ws layout (bytes):
//   WT  @ 0MB  : [4][1024][1024] bf16 (w_q^T, w_k^T, w_v^T, w_o^T)  8MB
//   Xb  @ 8MB  : [3][4096][1024] bf16 (q,k,v converted)            24MB
//   Qh  @ 32MB : [32][2048][64]  bf16 (scaled by 0.125*log2e)       8MB
//   Kh  @ 40MB : [32][2048][64]  bf16                               8MB
//   Vt  @ 48MB : [32][64][2048]  bf16 (per-head transposed V)       8MB
//   Ob  @ 56MB : [4096][1024]    bf16 (attention output)            8MB

using bf16x8 = __attribute__((ext_vector_type(8))) short;
using f32x4  = __attribute__((ext_vector_type(4))) float;
using u32x4  = __attribute__((ext_vector_type(4))) unsigned;
typedef unsigned short u16;
using u16x4 = __attribute__((ext_vector_type(4))) u16;
using u16x8 = __attribute__((ext_vector_type(8))) u16;

#define GLDS16(g, l) __builtin_amdgcn_global_load_lds( \
    (const __attribute__((address_space(1))) void*)(g), \
    (__attribute__((address_space(3))) void*)(l), 16, 0, 0)

#if __has_builtin(__builtin_amdgcn_exp2f)
#define EXP2(x) __builtin_amdgcn_exp2f(x)
#else
#define EXP2(x) exp2f(x)
#endif

// Raw s_barrier is IntrNoMem: pair it with compiler memory fences so LDS
// reads/writes cannot be moved across it at compile time.
__device__ __forceinline__ void block_sync() {
  __builtin_amdgcn_sched_barrier(0);
  asm volatile("" ::: "memory");
  __builtin_amdgcn_s_barrier();
  asm volatile("" ::: "memory");
  __builtin_amdgcn_sched_barrier(0);
}

__device__ __forceinline__ u16 f2bf(float f) {
  unsigned u = __builtin_bit_cast(unsigned, f);
  u += 0x7fffu + ((u >> 16) & 1u);
  return (u16)(u >> 16);
}

// packed f32->bf16 RNE (no builtin on gfx950; T12 primitive)
__device__ __forceinline__ unsigned cvt_pk_bf16(float lo, float hi) {
  unsigned r;
  asm("v_cvt_pk_bf16_f32 %0, %1, %2" : "=v"(r) : "v"(lo), "v"(hi));
  return r;
}

__device__ __forceinline__ float fmax3(float a, float b, float c) {
  return fmaxf(fmaxf(a, b), c);  // clang fuses to v_max3_f32
}

// ---------- kernel 1: weight transpose+convert: WT[z][n][k] = bf16(w_z[k][n]) ----------
__global__ __launch_bounds__(256) void wtrans_kernel(
    const float* __restrict__ wq, const float* __restrict__ wk,
    const float* __restrict__ wv, const float* __restrict__ wo,
    u16* __restrict__ dst) {
  __shared__ float t[32][33];
  const int z = blockIdx.z;
  const float* src = (z == 0) ? wq : (z == 1) ? wk : (z == 2) ? wv : wo;
  u16* d = dst + (size_t)z * 1024 * 1024;
  const int tx = threadIdx.x & 31, ty = threadIdx.x >> 5;
  const int bx = blockIdx.x * 32, by = blockIdx.y * 32;
#pragma unroll
  for (int j = 0; j < 4; j++)
    t[ty + j * 8][tx] = src[(size_t)(by + ty + j * 8) * 1024 + bx + tx];
  __syncthreads();
#pragma unroll
  for (int j = 0; j < 4; j++)
    d[(size_t)(bx + ty + j * 8) * 1024 + by + tx] = f2bf(t[tx][ty + j * 8]);
}

// ---------- kernel 2: convert q,k,v fp32 -> bf16 ----------
__global__ __launch_bounds__(256) void cvt_in_kernel(
    const float* __restrict__ q, const float* __restrict__ k,
    const float* __restrict__ v, u16* __restrict__ dst) {
  const int z = blockIdx.y;
  const float* src = (z == 0) ? q : (z == 1) ? k : v;
  u16* d = dst + (size_t)z * 4096 * 1024;
  size_t i = ((size_t)blockIdx.x * 256 + threadIdx.x) * 4;
  float4 f = *(const float4*)(src + i);
  uint2 o2 = make_uint2(cvt_pk_bf16(f.x, f.y), cvt_pk_bf16(f.z, f.w));
  *(uint2*)(d + i) = o2;
}

// ---------- shared GEMM core: 128x128 tile, BK=64, swizzled LDS, global_load_lds ----------
__device__ __forceinline__ void gemm128(const u16* __restrict__ A,
                                        const u16* __restrict__ B,
                                        int arow0, int bcol0,
                                        u16* ldsA, u16* ldsB,
                                        f32x4 acc[4][4]) {
  const int tid = threadIdx.x;
  const int lane = tid & 63, wave = tid >> 6;
  const int lr = lane & 15, lg = lane >> 4;
  const int wr = (wave >> 1) * 64, wc = (wave & 1) * 64;
  for (int kt = 0; kt < 1024; kt += 64) {
#pragma unroll
    for (int i = 0; i < 4; i++) {
      int o = (i * 256 + tid) * 8;
      int row = o >> 6, ch = (o >> 3) & 7;
      int sc = (ch ^ (row & 7)) << 3;  // inverse-swizzled source chunk
      GLDS16(A + (size_t)(arow0 + row) * 1024 + kt + sc, &ldsA[o]);
      GLDS16(B + (size_t)(bcol0 + row) * 1024 + kt + sc, &ldsB[o]);
    }
    __syncthreads();
#pragma unroll
    for (int kk = 0; kk < 2; kk++) {
      bf16x8 af[4], bfr[4];
      const int ke = kk * 32 + lg * 8;
#pragma unroll
      for (int m = 0; m < 4; m++) {
        int row = wr + m * 16 + lr;
        af[m] = *(const bf16x8*)&ldsA[row * 64 + (ke ^ ((row & 7) << 3))];
      }
#pragma unroll
      for (int n = 0; n < 4; n++) {
        int row = wc + n * 16 + lr;
        bfr[n] = *(const bf16x8*)&ldsB[row * 64 + (ke ^ ((row & 7) << 3))];
      }
#pragma unroll
      for (int m = 0; m < 4; m++)
#pragma unroll
        for (int n = 0; n < 4; n++)
          acc[m][n] = __builtin_amdgcn_mfma_f32_16x16x32_bf16(af[m], bfr[n],
                                                              acc[m][n], 0, 0, 0);
    }
    __syncthreads();
  }
}

// ---------- kernel 3: QKV projections ----------
__global__ __launch_bounds__(256) void proj_kernel(
    const u16* __restrict__ Xb, const u16* __restrict__ WT,
    u16* __restrict__ Qh, u16* __restrict__ Kh, u16* __restrict__ Vt) {
  __shared__ u16 lds[16384];
  const int z = blockIdx.z;
  const u16* A = Xb + (size_t)z * 4096 * 1024;
  const u16* B = WT + (size_t)z * 1024 * 1024;
  const int arow0 = blockIdx.y * 128, bcol0 = blockIdx.x * 128;
  f32x4 acc[4][4] = {};
  gemm128(A, B, arow0, bcol0, lds, lds + 8192, acc);

  const int lane = threadIdx.x & 63, wave = threadIdx.x >> 6;
  const int lr = lane & 15, lg = lane >> 4;
  const int wr = (wave >> 1) * 64, wc = (wave & 1) * 64;

  if (z == 2) {
    // V: transpose through LDS -> Vt[(b*16+h)*64+d][s]
    u16* T = lds;  // [128 c][128 s], swizzled rows
#pragma unroll
    for (int m = 0; m < 4; m++)
#pragma unroll
      for (int n = 0; n < 4; n++)
#pragma unroll
        for (int r = 0; r < 4; r++) {
          int sl = wr + m * 16 + lg * 4 + r;
          int cl = wc + n * 16 + lr;
          T[cl * 128 + (sl ^ ((cl & 7) << 3))] = f2bf(acc[m][n][r]);
        }
    __syncthreads();
    const int t = threadIdx.x;
    const int cl = t >> 1, s0 = (t & 1) * 64;
    const int gc = bcol0 + cl;
    const size_t vrow = ((size_t)(arow0 >> 11) * 16 + (gc >> 6)) * 64 + (gc & 63);
#pragma unroll
    for (int j = 0; j < 8; j++) {
      int sl = s0 + j * 8;
      u16x8 vv = *(const u16x8*)&T[cl * 128 + (sl ^ ((cl & 7) << 3))];
      *(u16x8*)&Vt[vrow * 2048 + (size_t)((arow0 & 2047) + sl)] = vv;
    }
  } else {
    const float scale = (z == 0) ? 0.18033688f : 1.0f;  // 0.125 * log2(e)
    u16* dst = (z == 0) ? Qh : Kh;
#pragma unroll
    for (int m = 0; m < 4; m++)
#pragma unroll
      for (int n = 0; n < 4; n++)
#pragma unroll
        for (int r = 0; r < 4; r++) {
          int gr = arow0 + wr + m * 16 + lg * 4 + r;
          int gc = bcol0 + wc + n * 16 + lr;
          size_t idx = (((size_t)(gr >> 11) * 16 + (gc >> 6)) * 2048 +
                        (gr & 2047)) * 64 + (gc & 63);
          dst[idx] = f2bf(acc[m][n][r] * scale);
        }
  }
}

// ---------- kernel 4: flash attention (swapped QK^T, P in registers) ----------
// 512 blocks (XCD-swizzled) x 8 waves, 128 q-rows per block, 16 per wave.
// Quad-buffered K/V (64KB LDS), 2-deep prefetch, steady vmcnt(6);
// launch_bounds(512,4) -> 2 blocks/CU = 16 waves/CU, grid exactly resident.
// Per-tile barrier pair now serves 128 q-rows (2x R8) -> sync/stage overhead
// halves per unit work; COMPUTE math identical to R8 (verified).
// S^T = mfma(K-frag, Q-frag): lane owns q = lane&15; K rows fed through
// permutation κ(n,a)=32(n>>1)+8(a>>2)+4(n&1)+(a&3) so the lane's 16 keys are
// exactly the PV A-fragment sets {8*lg..+7} u {32+8*lg..+7} -> zero exchange.
// K bank swizzle h(kr)=(kr&3)|(((kr>>3)&1)<<2): bijective on bank-groups for
// every 8 consecutive lanes.
__global__ __launch_bounds__(512, 4) void attn_kernel(
    const u16* __restrict__ Qh, const u16* __restrict__ Kh,
    const u16* __restrict__ Vt, u16* __restrict__ Ob) {
  __shared__ u16 kt[4][64 * 64];  // K tiles [key][d], h-swizzled rows
  __shared__ u16 vt[4][64 * 64];  // V^T tiles [d][s], xor-swizzled rows
  const int tid = threadIdx.x;
  const int lane = tid & 63, wave = tid >> 6;
  const int lr = lane & 15, lg = lane >> 4;
  // bijective XCD swizzle (512 % 8 == 0): each XCD owns 4 complete bh's
  const int id = blockIdx.x;
  const int swz = (id & 7) * 64 + (id >> 3);
  const int bh = swz >> 4;
  const int q0 = (swz & 15) * 128;
  const u16* Qb = Qh + ((size_t)bh * 2048 + q0) * 64;
  const u16* Kb = Kh + (size_t)bh * 2048 * 64;
  const u16* Vb = Vt + (size_t)bh * 64 * 2048;

  // Q fragment (B-operand of swapped QK^T); wave owns q-rows [wave*16, +16)
  bf16x8 aq[2];
#pragma unroll
  for (int kk = 0; kk < 2; kk++)
    aq[kk] = *(const bf16x8*)(Qb + (wave * 16 + lr) * 64 + kk * 32 + lg * 8);

  // K A-operand LDS offsets: perm κ, swizzle h (h depends only on lr)
  const int hsw = (lr & 3) | (((lr >> 2) & 1) << 2);
  int koff[2][4];
#pragma unroll
  for (int n = 0; n < 4; n++) {
    int kr = 32 * (n >> 1) + 8 * (lr >> 2) + 4 * (n & 1) + (lr & 3);
#pragma unroll
    for (int kk = 0; kk < 2; kk++)
      koff[kk][n] = kr * 64 + ((kk * 32 + lg * 8) ^ (hsw << 3));
  }
  // V B-operand LDS offsets
  int voff[2][4];
#pragma unroll
  for (int n = 0; n < 4; n++) {
    int d = n * 16 + lr;
#pragma unroll
    for (int ks = 0; ks < 2; ks++)
      voff[ks][n] = d * 64 + ((ks * 32 + lg * 8) ^ ((d & 7) << 3));
  }

  // staging: 512 threads cover one 64x64 K tile + one 64x64 V tile,
  // 1 chunk of 16B each; row = tid>>3, ch = tid&7
  const int o0 = tid * 8;
  const int srow = tid >> 3, sch = tid & 7;
  const int hk = (srow & 3) | (((srow >> 3) & 1) << 2);
  const u16* kg = Kb + (size_t)srow * 64 + ((sch ^ hk) << 3);
  const u16* vg = Vb + (size_t)srow * 2048 + ((sch ^ (srow & 7)) << 3);

  f32x4 oacc[4] = {};
  float mrun = -1e30f, lrun = 0.f;

  auto STAGE = [&](int t, int b) {  // b literal at call site; 2 insts/thread
    GLDS16(kg + (size_t)t * 4096, &kt[0][0] + b * 4096 + o0);
    GLDS16(vg + t * 64, &vt[0][0] + b * 4096 + o0);
  };

  auto COMPUTE = [&](int cur) {  // cur literal at call site
    // S^T tile: sacc[n][r] = S[key κ(n, lg*4+r)][q=lr] (log2 domain)
    f32x4 sacc[4] = {};
    __builtin_amdgcn_s_setprio(1);
#pragma unroll
    for (int kk = 0; kk < 2; kk++) {
#pragma unroll
      for (int n = 0; n < 4; n++) {
        bf16x8 ka = *(const bf16x8*)&kt[cur][koff[kk][n]];
        sacc[n] = __builtin_amdgcn_mfma_f32_16x16x32_bf16(ka, aq[kk],
                                                          sacc[n], 0, 0, 0);
      }
    }
    __builtin_amdgcn_s_setprio(0);
    // row max: 7 max3 + 1 fmax in-lane, then 2 cross-lane steps
    float t0 = fmax3(sacc[0][0], sacc[0][1], sacc[0][2]);
    float t1 = fmax3(sacc[0][3], sacc[1][0], sacc[1][1]);
    float t2 = fmax3(sacc[1][2], sacc[1][3], sacc[2][0]);
    float t3 = fmax3(sacc[2][1], sacc[2][2], sacc[2][3]);
    float t4 = fmax3(sacc[3][0], sacc[3][1], sacc[3][2]);
    float mx = fmaxf(fmax3(t0, t1, t2), fmax3(t3, t4, sacc[3][3]));
    mx = fmaxf(mx, __shfl_xor(mx, 16));
    mx = fmaxf(mx, __shfl_xor(mx, 32));
    float mnew = fmaxf(mrun, mx);
    // defer-max (T13): skip rescale when growth <= 8 (log2 domain -> p <= 256)
    if (__all(mx - mrun <= 8.0f)) {
      mnew = mrun;
    } else {
      float corr = EXP2(mrun - mnew);
      mrun = mnew;
      lrun *= corr;
      float cr[4];
#pragma unroll
      for (int r = 0; r < 4; r++) cr[r] = __shfl(corr, lg * 4 + r);
#pragma unroll
      for (int n = 0; n < 4; n++)
#pragma unroll
        for (int r = 0; r < 4; r++) oacc[n][r] *= cr[r];
    }
    // p = exp2(s - m), in place; row-sum
    float psum = 0.f;
#pragma unroll
    for (int n = 0; n < 4; n++)
#pragma unroll
      for (int r = 0; r < 4; r++) {
        float p = EXP2(sacc[n][r] - mnew);
        sacc[n][r] = p;
        psum += p;
      }
    psum += __shfl_xor(psum, 16);
    psum += __shfl_xor(psum, 32);
    lrun += psum;
    // pack P into PV A-fragments via v_cvt_pk_bf16_f32
    u32x4 w0 = {cvt_pk_bf16(sacc[0][0], sacc[0][1]),
                cvt_pk_bf16(sacc[0][2], sacc[0][3]),
                cvt_pk_bf16(sacc[1][0], sacc[1][1]),
                cvt_pk_bf16(sacc[1][2], sacc[1][3])};
    u32x4 w1 = {cvt_pk_bf16(sacc[2][0], sacc[2][1]),
                cvt_pk_bf16(sacc[2][2], sacc[2][3]),
                cvt_pk_bf16(sacc[3][0], sacc[3][1]),
                cvt_pk_bf16(sacc[3][2], sacc[3][3])};
    bf16x8 pa0 = __builtin_bit_cast(bf16x8, w0);
    bf16x8 pa1 = __builtin_bit_cast(bf16x8, w1);
    // O += P V
    __builtin_amdgcn_s_setprio(1);
#pragma unroll
    for (int ks = 0; ks < 2; ks++) {
      bf16x8 ap = ks ? pa1 : pa0;
      bf16x8 bv[4];
#pragma unroll
      for (int n = 0; n < 4; n++)
        bv[n] = *(const bf16x8*)&vt[cur][voff[ks][n]];
#pragma unroll
      for (int n = 0; n < 4; n++)
        oacc[n] = __builtin_amdgcn_mfma_f32_16x16x32_bf16(ap, bv[n],
                                                          oacc[n], 0, 0, 0);
    }
    __builtin_amdgcn_s_setprio(0);
  };

#define VMC6 asm volatile("s_waitcnt vmcnt(6)" ::: "memory")
#define VMC4 asm volatile("s_waitcnt vmcnt(4)" ::: "memory")
#define VMC2 asm volatile("s_waitcnt vmcnt(2)" ::: "memory")
#define VMC0 asm volatile("s_waitcnt vmcnt(0)" ::: "memory")
  STAGE(0, 0); STAGE(1, 1); STAGE(2, 2);
  // quad-buffered, 2 tiles in flight; unrolled x4 so buf indices are literals
  for (int t = 0; t < 28; t += 4) {
    STAGE(t + 3, 3); VMC6; block_sync(); COMPUTE(0); block_sync();
    STAGE(t + 4, 0); VMC6; block_sync(); COMPUTE(1); block_sync();
    STAGE(t + 5, 1); VMC6; block_sync(); COMPUTE(2); block_sync();
    STAGE(t + 6, 2); VMC6; block_sync(); COMPUTE(3); block_sync();
  }
  // staged 0..30, computed 0..27
  STAGE(31, 3); VMC6; block_sync(); COMPUTE(0); block_sync();  // tile 28
  VMC4; block_sync(); COMPUTE(1); block_sync();                // tile 29
  VMC2; block_sync(); COMPUTE(2); block_sync();                // tile 30
  VMC0; block_sync(); COMPUTE(3);                              // tile 31
#undef VMC6
#undef VMC4
#undef VMC2
#undef VMC0

  // epilogue: normalize (inv lives at q=lr; oacc rows are q=lg*4+r)
  const int b = bh >> 4, h = bh & 15;
  float inv = 1.0f / lrun;
  float ivr[4];
#pragma unroll
  for (int r = 0; r < 4; r++) ivr[r] = __shfl(inv, lg * 4 + r);
#pragma unroll
  for (int r = 0; r < 4; r++) {
    int qrow = q0 + wave * 16 + lg * 4 + r;
#pragma unroll
    for (int n = 0; n < 4; n++) {
      int d = n * 16 + lr;
      Ob[((size_t)b * 2048 + qrow) * 1024 + h * 64 + d] = f2bf(oacc[n][r] * ivr[r]);
    }
  }
}

// ---------- kernel 5: output projection (128x64 tile -> 512 blocks, 2/CU) ----------
__global__ __launch_bounds__(256) void outproj_kernel(
    const u16* __restrict__ Ob, const u16* __restrict__ WoT,
    float* __restrict__ out) {
  __shared__ u16 ldsA[128 * 64];  // 16KB, swizzled rows
  __shared__ u16 ldsB[64 * 64];   //  8KB, swizzled rows
  const int tid = threadIdx.x;
  const int lane = tid & 63, wave = tid >> 6;
  const int lr = lane & 15, lg = lane >> 4;
  const int wr = (wave >> 1) * 64;  // M offset (0/64)
  const int wc = (wave & 1) * 32;   // N offset (0/32)
  const int arow0 = blockIdx.y * 128, bcol0 = blockIdx.x * 64;
  f32x4 acc[4][2] = {};
  for (int kt = 0; kt < 1024; kt += 64) {
#pragma unroll
    for (int i = 0; i < 4; i++) {
      int o = (i * 256 + tid) * 8;
      int row = o >> 6, ch = (o >> 3) & 7;
      int sc = (ch ^ (row & 7)) << 3;
      GLDS16(Ob + (size_t)(arow0 + row) * 1024 + kt + sc, &ldsA[o]);
    }
#pragma unroll
    for (int i = 0; i < 2; i++) {
      int o = (i * 256 + tid) * 8;
      int row = o >> 6, ch = (o >> 3) & 7;
      int sc = (ch ^ (row & 7)) << 3;
      GLDS16(WoT + (size_t)(bcol0 + row) * 1024 + kt + sc, &ldsB[o]);
    }
    __syncthreads();
#pragma unroll
    for (int kk = 0; kk < 2; kk++) {
      const int ke = kk * 32 + lg * 8;
      bf16x8 af[4], bfr[2];
#pragma unroll
      for (int m = 0; m < 4; m++) {
        int row = wr + m * 16 + lr;
        af[m] = *(const bf16x8*)&ldsA[row * 64 + (ke ^ ((row & 7) << 3))];
      }
#pragma unroll
      for (int n = 0; n < 2; n++) {
        int row = wc + n * 16 + lr;
        bfr[n] = *(const bf16x8*)&ldsB[row * 64 + (ke ^ ((row & 7) << 3))];
      }
#pragma unroll
      for (int m = 0; m < 4; m++)
#pragma unroll
        for (int n = 0; n < 2; n++)
          acc[m][n] = __builtin_amdgcn_mfma_f32_16x16x32_bf16(af[m], bfr[n],
                                                              acc[m][n], 0, 0, 0);
    }
    __syncthreads();
  }
#pragma unroll
  for (int m = 0; m < 4; m++)
#pragma unroll
    for (int n = 0; n < 2; n++)
#pragma unroll
      for (int r = 0; r < 4; r++) {
        int gr = arow0 + wr + m * 16 + lg * 4 + r;
        int gc = bcol0 + wc + n * 16 + lr;
        out[(size_t)gr * 1024 + gc] = acc[m][n][r];
      }
}

extern "C" void kernel_launch(void* const* d_in, const int* in_sizes, int n_in,
                              void* d_out, int out_size, void* d_ws, size_t ws_size,
                              hipStream_t stream) {
  const float* q  = (const float*)d_in[0];
  const float* k  = (const float*)d_in[1];
  const float* v  = (const float*)d_in[2];
  const float* wq = (const float*)d_in[3];
  const float* wk = (const float*)d_in[4];
  const float* wv = (const float*)d_in[5];
  const float* wo = (const float*)d_in[6];
  float* out = (float*)d_out;
  char* ws = (char*)d_ws;

  u16* WT = (u16*)ws;                                    // [4][1024][1024]
  u16* Xb = (u16*)(ws + (size_t)8  * 1024 * 1024);       // [3][4096][1024]
  u16* Qh = (u16*)(ws + (size_t)32 * 1024 * 1024);       // [32][2048][64]
  u16* Kh = (u16*)(ws + (size_t)40 * 1024 * 1024);       // [32][2048][64]
  u16* Vt = (u16*)(ws + (size_t)48 * 1024 * 1024);       // [32][64][2048]
  u16* Ob = (u16*)(ws + (size_t)56 * 1024 * 1024);       // [4096][1024]

  wtrans_kernel<<<dim3(32, 32, 4), 256, 0, stream>>>(wq, wk, wv, wo, WT);
  cvt_in_kernel<<<dim3(4096, 3), 256, 0, stream>>>(q, k, v, Xb);
  proj_kernel<<<dim3(8, 32, 3), 256, 0, stream>>>(Xb, WT, Qh, Kh, Vt);
  attn_kernel<<<dim3(512), 512, 0, stream>>>(Qh, Kh, Vt, Ob);
  outproj_kernel<<<dim3(16, 32), 256, 0, stream>>>(Ob, WT + (size_t)3 * 1024 * 1024, out);
}

// Round 10
// 128.516 us; speedup vs baseline: 1.2536x; 1.0322x over previous
//
#include <hip/hip_runtime.h>
#include <hip/hip_bf16.h>

// B=2, S=2048, H=16, D=64, D_MODEL=1024, M=B*S=4096
// ws layout (bytes):
//   WT  @ 0MB  : [4][1024][1024] bf16 (w_q^T, w_k^T, w_v^T, w_o^T)  8MB
//   Qh  @ 32MB : [32][2048][64]  bf16 (scaled by 0.125*log2e)       8MB
//   Kh  @ 40MB : [32][2048][64]  bf16                               8MB
//   Vt  @ 48MB : [32][64][2048]  bf16 (per-head transposed V)       8MB
//   Ob  @ 56MB : [4096][1024]    bf16 (attention output)            8MB

using bf16x8 = __attribute__((ext_vector_type(8))) short;
using f32x4  = __attribute__((ext_vector_type(4))) float;
using u32x4  = __attribute__((ext_vector_type(4))) unsigned;
typedef unsigned short u16;
using u16x4 = __attribute__((ext_vector_type(4))) u16;
using u16x8 = __attribute__((ext_vector_type(8))) u16;

#define GLDS16(g, l) __builtin_amdgcn_global_load_lds( \
    (const __attribute__((address_space(1))) void*)(g), \
    (__attribute__((address_space(3))) void*)(l), 16, 0, 0)

#if __has_builtin(__builtin_amdgcn_exp2f)
#define EXP2(x) __builtin_amdgcn_exp2f(x)
#else
#define EXP2(x) exp2f(x)
#endif

// Raw s_barrier is IntrNoMem: pair it with compiler memory fences so LDS
// reads/writes cannot be moved across it at compile time.
__device__ __forceinline__ void block_sync() {
  __builtin_amdgcn_sched_barrier(0);
  asm volatile("" ::: "memory");
  __builtin_amdgcn_s_barrier();
  asm volatile("" ::: "memory");
  __builtin_amdgcn_sched_barrier(0);
}

__device__ __forceinline__ u16 f2bf(float f) {
  unsigned u = __builtin_bit_cast(unsigned, f);
  u += 0x7fffu + ((u >> 16) & 1u);
  return (u16)(u >> 16);
}

// packed f32->bf16 RNE (no builtin on gfx950; T12 primitive)
__device__ __forceinline__ unsigned cvt_pk_bf16(float lo, float hi) {
  unsigned r;
  asm("v_cvt_pk_bf16_f32 %0, %1, %2" : "=v"(r) : "v"(lo), "v"(hi));
  return r;
}

__device__ __forceinline__ float fmax3(float a, float b, float c) {
  return fmaxf(fmaxf(a, b), c);  // clang fuses to v_max3_f32
}

// ---------- kernel 1: weight transpose+convert: WT[z][n][k] = bf16(w_z[k][n]) ----------
__global__ __launch_bounds__(256) void wtrans_kernel(
    const float* __restrict__ wq, const float* __restrict__ wk,
    const float* __restrict__ wv, const float* __restrict__ wo,
    u16* __restrict__ dst) {
  __shared__ float t[32][33];
  const int z = blockIdx.z;
  const float* src = (z == 0) ? wq : (z == 1) ? wk : (z == 2) ? wv : wo;
  u16* d = dst + (size_t)z * 1024 * 1024;
  const int tx = threadIdx.x & 31, ty = threadIdx.x >> 5;
  const int bx = blockIdx.x * 32, by = blockIdx.y * 32;
#pragma unroll
  for (int j = 0; j < 4; j++)
    t[ty + j * 8][tx] = src[(size_t)(by + ty + j * 8) * 1024 + bx + tx];
  __syncthreads();
#pragma unroll
  for (int j = 0; j < 4; j++)
    d[(size_t)(bx + ty + j * 8) * 1024 + by + tx] = f2bf(t[tx][ty + j * 8]);
}

// ---------- kernel 2: fused QKV projections (cvt folded in, XCD-chunked) ----------
// 768 blocks 1-D; xcd=id&7 owns y-panels [4*xcd, 4*xcd+4) x all 8 bcols per z
// -> each fp32 A-panel fetched by exactly ONE XCD; B (6MB) L3-hot.
// A: fp32 -> bf16 reg-staged (2x float4 -> 4 cvt_pk -> swizzled ds_write_b128).
// B: pre-swizzled global_load_lds, issued first to fly under A load+convert.
__global__ __launch_bounds__(256) void proj_kernel(
    const float* __restrict__ qf, const float* __restrict__ kf,
    const float* __restrict__ vf, const u16* __restrict__ WT,
    u16* __restrict__ Qh, u16* __restrict__ Kh, u16* __restrict__ Vt) {
  __shared__ u16 lds[16384];
  u16* ldsA = lds;
  u16* ldsB = lds + 8192;
  const int id = blockIdx.x;
  const int xcd = id & 7, l = id >> 3;      // l in [0,96)
  const int z = l >> 5, rem = l & 31;       // 32 blocks per XCD per z
  const int by = xcd * 4 + (rem >> 3);      // 4 y-panels per XCD
  const int bx = rem & 7;
  const int arow0 = by * 128, bcol0 = bx * 128;
  const float* A = (z == 0) ? qf : (z == 1) ? kf : vf;
  const u16* Bw = WT + (size_t)z * 1024 * 1024;

  const int tid = threadIdx.x;
  const int lane = tid & 63, wave = tid >> 6;
  const int lr = lane & 15, lg = lane >> 4;
  const int wr = (wave >> 1) * 64, wc = (wave & 1) * 64;
  f32x4 acc[4][4] = {};

  for (int kt = 0; kt < 1024; kt += 64) {
    // B first: async loads in flight during A's load+convert
#pragma unroll
    for (int i = 0; i < 4; i++) {
      int o = (i * 256 + tid) * 8;
      int row = o >> 6, ch = (o >> 3) & 7;
      int sc = (ch ^ (row & 7)) << 3;  // inverse-swizzled source chunk
      GLDS16(Bw + (size_t)(bcol0 + row) * 1024 + kt + sc, &ldsB[o]);
    }
    // A: fp32 global -> cvt_pk -> swizzled LDS write
#pragma unroll
    for (int i = 0; i < 4; i++) {
      int o = (i * 256 + tid) * 8;
      int row = o >> 6, ch = (o >> 3) & 7;
      const float* ap = A + (size_t)(arow0 + row) * 1024 + kt + ch * 8;
      float4 f0 = *(const float4*)ap;
      float4 f1 = *(const float4*)(ap + 4);
      u32x4 w = {cvt_pk_bf16(f0.x, f0.y), cvt_pk_bf16(f0.z, f0.w),
                 cvt_pk_bf16(f1.x, f1.y), cvt_pk_bf16(f1.z, f1.w)};
      *(u32x4*)&ldsA[row * 64 + ((ch ^ (row & 7)) << 3)] = w;
    }
    __syncthreads();
#pragma unroll
    for (int kk = 0; kk < 2; kk++) {
      bf16x8 af[4], bfr[4];
      const int ke = kk * 32 + lg * 8;
#pragma unroll
      for (int m = 0; m < 4; m++) {
        int row = wr + m * 16 + lr;
        af[m] = *(const bf16x8*)&ldsA[row * 64 + (ke ^ ((row & 7) << 3))];
      }
#pragma unroll
      for (int n = 0; n < 4; n++) {
        int row = wc + n * 16 + lr;
        bfr[n] = *(const bf16x8*)&ldsB[row * 64 + (ke ^ ((row & 7) << 3))];
      }
#pragma unroll
      for (int m = 0; m < 4; m++)
#pragma unroll
        for (int n = 0; n < 4; n++)
          acc[m][n] = __builtin_amdgcn_mfma_f32_16x16x32_bf16(af[m], bfr[n],
                                                              acc[m][n], 0, 0, 0);
    }
    __syncthreads();
  }

  if (z == 2) {
    // V: transpose through LDS -> Vt[(b*16+h)*64+d][s]
    u16* T = lds;  // [128 c][128 s], swizzled rows
#pragma unroll
    for (int m = 0; m < 4; m++)
#pragma unroll
      for (int n = 0; n < 4; n++)
#pragma unroll
        for (int r = 0; r < 4; r++) {
          int sl = wr + m * 16 + lg * 4 + r;
          int cl = wc + n * 16 + lr;
          T[cl * 128 + (sl ^ ((cl & 7) << 3))] = f2bf(acc[m][n][r]);
        }
    __syncthreads();
    const int t = threadIdx.x;
    const int cl = t >> 1, s0 = (t & 1) * 64;
    const int gc = bcol0 + cl;
    const size_t vrow = ((size_t)(arow0 >> 11) * 16 + (gc >> 6)) * 64 + (gc & 63);
#pragma unroll
    for (int j = 0; j < 8; j++) {
      int sl = s0 + j * 8;
      u16x8 vv = *(const u16x8*)&T[cl * 128 + (sl ^ ((cl & 7) << 3))];
      *(u16x8*)&Vt[vrow * 2048 + (size_t)((arow0 & 2047) + sl)] = vv;
    }
  } else {
    const float scale = (z == 0) ? 0.18033688f : 1.0f;  // 0.125 * log2(e)
    u16* dst = (z == 0) ? Qh : Kh;
#pragma unroll
    for (int m = 0; m < 4; m++)
#pragma unroll
      for (int n = 0; n < 4; n++)
#pragma unroll
        for (int r = 0; r < 4; r++) {
          int gr = arow0 + wr + m * 16 + lg * 4 + r;
          int gc = bcol0 + wc + n * 16 + lr;
          size_t idx = (((size_t)(gr >> 11) * 16 + (gc >> 6)) * 2048 +
                        (gr & 2047)) * 64 + (gc & 63);
          dst[idx] = f2bf(acc[m][n][r] * scale);
        }
  }
}

// ---------- kernel 3: flash attention (swapped QK^T, P in registers) ----------
// 512 blocks (XCD-swizzled) x 8 waves, 128 q-rows per block, 16 per wave.
// Quad-buffered K/V (64KB LDS), 2-deep prefetch, steady vmcnt(6);
// launch_bounds(512,4) -> 2 blocks/CU = 16 waves/CU, grid exactly resident.
// S^T = mfma(K-frag, Q-frag): lane owns q = lane&15; K rows fed through
// permutation κ(n,a)=32(n>>1)+8(a>>2)+4(n&1)+(a&3) so the lane's 16 keys are
// exactly the PV A-fragment sets {8*lg..+7} u {32+8*lg..+7} -> zero exchange.
// K bank swizzle h(kr)=(kr&3)|(((kr>>3)&1)<<2): bijective on bank-groups for
// every 8 consecutive lanes.
__global__ __launch_bounds__(512, 4) void attn_kernel(
    const u16* __restrict__ Qh, const u16* __restrict__ Kh,
    const u16* __restrict__ Vt, u16* __restrict__ Ob) {
  __shared__ u16 kt[4][64 * 64];  // K tiles [key][d], h-swizzled rows
  __shared__ u16 vt[4][64 * 64];  // V^T tiles [d][s], xor-swizzled rows
  const int tid = threadIdx.x;
  const int lane = tid & 63, wave = tid >> 6;
  const int lr = lane & 15, lg = lane >> 4;
  // bijective XCD swizzle (512 % 8 == 0): each XCD owns 4 complete bh's
  const int id = blockIdx.x;
  const int swz = (id & 7) * 64 + (id >> 3);
  const int bh = swz >> 4;
  const int q0 = (swz & 15) * 128;
  const u16* Qb = Qh + ((size_t)bh * 2048 + q0) * 64;
  const u16* Kb = Kh + (size_t)bh * 2048 * 64;
  const u16* Vb = Vt + (size_t)bh * 64 * 2048;

  // Q fragment (B-operand of swapped QK^T); wave owns q-rows [wave*16, +16)
  bf16x8 aq[2];
#pragma unroll
  for (int kk = 0; kk < 2; kk++)
    aq[kk] = *(const bf16x8*)(Qb + (wave * 16 + lr) * 64 + kk * 32 + lg * 8);

  // K A-operand LDS offsets: perm κ, swizzle h (h depends only on lr)
  const int hsw = (lr & 3) | (((lr >> 2) & 1) << 2);
  int koff[2][4];
#pragma unroll
  for (int n = 0; n < 4; n++) {
    int kr = 32 * (n >> 1) + 8 * (lr >> 2) + 4 * (n & 1) + (lr & 3);
#pragma unroll
    for (int kk = 0; kk < 2; kk++)
      koff[kk][n] = kr * 64 + ((kk * 32 + lg * 8) ^ (hsw << 3));
  }
  // V B-operand LDS offsets
  int voff[2][4];
#pragma unroll
  for (int n = 0; n < 4; n++) {
    int d = n * 16 + lr;
#pragma unroll
    for (int ks = 0; ks < 2; ks++)
      voff[ks][n] = d * 64 + ((ks * 32 + lg * 8) ^ ((d & 7) << 3));
  }

  // staging: 512 threads cover one 64x64 K tile + one 64x64 V tile,
  // 1 chunk of 16B each; row = tid>>3, ch = tid&7
  const int o0 = tid * 8;
  const int srow = tid >> 3, sch = tid & 7;
  const int hk = (srow & 3) | (((srow >> 3) & 1) << 2);
  const u16* kg = Kb + (size_t)srow * 64 + ((sch ^ hk) << 3);
  const u16* vg = Vb + (size_t)srow * 2048 + ((sch ^ (srow & 7)) << 3);

  f32x4 oacc[4] = {};
  float mrun = -1e30f, lrun = 0.f;

  auto STAGE = [&](int t, int b) {  // b literal at call site; 2 insts/thread
    GLDS16(kg + (size_t)t * 4096, &kt[0][0] + b * 4096 + o0);
    GLDS16(vg + t * 64, &vt[0][0] + b * 4096 + o0);
  };

  auto COMPUTE = [&](int cur) {  // cur literal at call site
    // S^T tile: sacc[n][r] = S[key κ(n, lg*4+r)][q=lr] (log2 domain)
    f32x4 sacc[4] = {};
    __builtin_amdgcn_s_setprio(1);
#pragma unroll
    for (int kk = 0; kk < 2; kk++) {
#pragma unroll
      for (int n = 0; n < 4; n++) {
        bf16x8 ka = *(const bf16x8*)&kt[cur][koff[kk][n]];
        sacc[n] = __builtin_amdgcn_mfma_f32_16x16x32_bf16(ka, aq[kk],
                                                          sacc[n], 0, 0, 0);
      }
    }
    __builtin_amdgcn_s_setprio(0);
    // row max: 7 max3 + 1 fmax in-lane, then 2 cross-lane steps
    float t0 = fmax3(sacc[0][0], sacc[0][1], sacc[0][2]);
    float t1 = fmax3(sacc[0][3], sacc[1][0], sacc[1][1]);
    float t2 = fmax3(sacc[1][2], sacc[1][3], sacc[2][0]);
    float t3 = fmax3(sacc[2][1], sacc[2][2], sacc[2][3]);
    float t4 = fmax3(sacc[3][0], sacc[3][1], sacc[3][2]);
    float mx = fmaxf(fmax3(t0, t1, t2), fmax3(t3, t4, sacc[3][3]));
    mx = fmaxf(mx, __shfl_xor(mx, 16));
    mx = fmaxf(mx, __shfl_xor(mx, 32));
    float mnew = fmaxf(mrun, mx);
    // defer-max (T13): skip rescale when growth <= 8 (log2 domain -> p <= 256)
    if (__all(mx - mrun <= 8.0f)) {
      mnew = mrun;
    } else {
      float corr = EXP2(mrun - mnew);
      mrun = mnew;
      lrun *= corr;
      float cr[4];
#pragma unroll
      for (int r = 0; r < 4; r++) cr[r] = __shfl(corr, lg * 4 + r);
#pragma unroll
      for (int n = 0; n < 4; n++)
#pragma unroll
        for (int r = 0; r < 4; r++) oacc[n][r] *= cr[r];
    }
    // p = exp2(s - m), in place; row-sum
    float psum = 0.f;
#pragma unroll
    for (int n = 0; n < 4; n++)
#pragma unroll
      for (int r = 0; r < 4; r++) {
        float p = EXP2(sacc[n][r] - mnew);
        sacc[n][r] = p;
        psum += p;
      }
    psum += __shfl_xor(psum, 16);
    psum += __shfl_xor(psum, 32);
    lrun += psum;
    // pack P into PV A-fragments via v_cvt_pk_bf16_f32
    u32x4 w0 = {cvt_pk_bf16(sacc[0][0], sacc[0][1]),
                cvt_pk_bf16(sacc[0][2], sacc[0][3]),
                cvt_pk_bf16(sacc[1][0], sacc[1][1]),
                cvt_pk_bf16(sacc[1][2], sacc[1][3])};
    u32x4 w1 = {cvt_pk_bf16(sacc[2][0], sacc[2][1]),
                cvt_pk_bf16(sacc[2][2], sacc[2][3]),
                cvt_pk_bf16(sacc[3][0], sacc[3][1]),
                cvt_pk_bf16(sacc[3][2], sacc[3][3])};
    bf16x8 pa0 = __builtin_bit_cast(bf16x8, w0);
    bf16x8 pa1 = __builtin_bit_cast(bf16x8, w1);
    // O += P V
    __builtin_amdgcn_s_setprio(1);
#pragma unroll
    for (int ks = 0; ks < 2; ks++) {
      bf16x8 ap = ks ? pa1 : pa0;
      bf16x8 bv[4];
#pragma unroll
      for (int n = 0; n < 4; n++)
        bv[n] = *(const bf16x8*)&vt[cur][voff[ks][n]];
#pragma unroll
      for (int n = 0; n < 4; n++)
        oacc[n] = __builtin_amdgcn_mfma_f32_16x16x32_bf16(ap, bv[n],
                                                          oacc[n], 0, 0, 0);
    }
    __builtin_amdgcn_s_setprio(0);
  };

#define VMC6 asm volatile("s_waitcnt vmcnt(6)" ::: "memory")
#define VMC4 asm volatile("s_waitcnt vmcnt(4)" ::: "memory")
#define VMC2 asm volatile("s_waitcnt vmcnt(2)" ::: "memory")
#define VMC0 asm volatile("s_waitcnt vmcnt(0)" ::: "memory")
  STAGE(0, 0); STAGE(1, 1); STAGE(2, 2);
  // quad-buffered, 2 tiles in flight; unrolled x4 so buf indices are literals
  for (int t = 0; t < 28; t += 4) {
    STAGE(t + 3, 3); VMC6; block_sync(); COMPUTE(0); block_sync();
    STAGE(t + 4, 0); VMC6; block_sync(); COMPUTE(1); block_sync();
    STAGE(t + 5, 1); VMC6; block_sync(); COMPUTE(2); block_sync();
    STAGE(t + 6, 2); VMC6; block_sync(); COMPUTE(3); block_sync();
  }
  // staged 0..30, computed 0..27
  STAGE(31, 3); VMC6; block_sync(); COMPUTE(0); block_sync();  // tile 28
  VMC4; block_sync(); COMPUTE(1); block_sync();                // tile 29
  VMC2; block_sync(); COMPUTE(2); block_sync();                // tile 30
  VMC0; block_sync(); COMPUTE(3);                              // tile 31
#undef VMC6
#undef VMC4
#undef VMC2
#undef VMC0

  // epilogue: normalize (inv lives at q=lr; oacc rows are q=lg*4+r)
  const int b = bh >> 4, h = bh & 15;
  float inv = 1.0f / lrun;
  float ivr[4];
#pragma unroll
  for (int r = 0; r < 4; r++) ivr[r] = __shfl(inv, lg * 4 + r);
#pragma unroll
  for (int r = 0; r < 4; r++) {
    int qrow = q0 + wave * 16 + lg * 4 + r;
#pragma unroll
    for (int n = 0; n < 4; n++) {
      int d = n * 16 + lr;
      Ob[((size_t)b * 2048 + qrow) * 1024 + h * 64 + d] = f2bf(oacc[n][r] * ivr[r]);
    }
  }
}

// ---------- kernel 4: output projection (128x64 tile, XCD-chunked 512 blocks) ----------
__global__ __launch_bounds__(256) void outproj_kernel(
    const u16* __restrict__ Ob, const u16* __restrict__ WoT,
    float* __restrict__ out) {
  __shared__ u16 ldsA[128 * 64];  // 16KB, swizzled rows
  __shared__ u16 ldsB[64 * 64];   //  8KB, swizzled rows
  const int tid = threadIdx.x;
  const int lane = tid & 63, wave = tid >> 6;
  const int lr = lane & 15, lg = lane >> 4;
  const int wr = (wave >> 1) * 64;  // M offset (0/64)
  const int wc = (wave & 1) * 32;   // N offset (0/32)
  // XCD-chunked: xcd owns 4 y-panels x all 16 x -> each A panel one XCD
  const int id = blockIdx.x;
  const int xcd = id & 7, l = id >> 3;   // l in [0,64)
  const int by = xcd * 4 + (l >> 4);     // 0..31
  const int bx = l & 15;                 // 0..15
  const int arow0 = by * 128, bcol0 = bx * 64;
  f32x4 acc[4][2] = {};
  for (int kt = 0; kt < 1024; kt += 64) {
#pragma unroll
    for (int i = 0; i < 4; i++) {
      int o = (i * 256 + tid) * 8;
      int row = o >> 6, ch = (o >> 3) & 7;
      int sc = (ch ^ (row & 7)) << 3;
      GLDS16(Ob + (size_t)(arow0 + row) * 1024 + kt + sc, &ldsA[o]);
    }
#pragma unroll
    for (int i = 0; i < 2; i++) {
      int o = (i * 256 + tid) * 8;
      int row = o >> 6, ch = (o >> 3) & 7;
      int sc = (ch ^ (row & 7)) << 3;
      GLDS16(WoT + (size_t)(bcol0 + row) * 1024 + kt + sc, &ldsB[o]);
    }
    __syncthreads();
#pragma unroll
    for (int kk = 0; kk < 2; kk++) {
      const int ke = kk * 32 + lg * 8;
      bf16x8 af[4], bfr[2];
#pragma unroll
      for (int m = 0; m < 4; m++) {
        int row = wr + m * 16 + lr;
        af[m] = *(const bf16x8*)&ldsA[row * 64 + (ke ^ ((row & 7) << 3))];
      }
#pragma unroll
      for (int n = 0; n < 2; n++) {
        int row = wc + n * 16 + lr;
        bfr[n] = *(const bf16x8*)&ldsB[row * 64 + (ke ^ ((row & 7) << 3))];
      }
#pragma unroll
      for (int m = 0; m < 4; m++)
#pragma unroll
        for (int n = 0; n < 2; n++)
          acc[m][n] = __builtin_amdgcn_mfma_f32_16x16x32_bf16(af[m], bfr[n],
                                                              acc[m][n], 0, 0, 0);
    }
    __syncthreads();
  }
#pragma unroll
  for (int m = 0; m < 4; m++)
#pragma unroll
    for (int n = 0; n < 2; n++)
#pragma unroll
      for (int r = 0; r < 4; r++) {
        int gr = arow0 + wr + m * 16 + lg * 4 + r;
        int gc = bcol0 + wc + n * 16 + lr;
        out[(size_t)gr * 1024 + gc] = acc[m][n][r];
      }
}

extern "C" void kernel_launch(void* const* d_in, const int* in_sizes, int n_in,
                              void* d_out, int out_size, void* d_ws, size_t ws_size,
                              hipStream_t stream) {
  const float* q  = (const float*)d_in[0];
  const float* k  = (const float*)d_in[1];
  const float* v  = (const float*)d_in[2];
  const float* wq = (const float*)d_in[3];
  const float* wk = (const float*)d_in[4];
  const float* wv = (const float*)d_in[5];
  const float* wo = (const float*)d_in[6];
  float* out = (float*)d_out;
  char* ws = (char*)d_ws;

  u16* WT = (u16*)ws;                                    // [4][1024][1024]
  u16* Qh = (u16*)(ws + (size_t)32 * 1024 * 1024);       // [32][2048][64]
  u16* Kh = (u16*)(ws + (size_t)40 * 1024 * 1024);       // [32][2048][64]
  u16* Vt = (u16*)(ws + (size_t)48 * 1024 * 1024);       // [32][64][2048]
  u16* Ob = (u16*)(ws + (size_t)56 * 1024 * 1024);       // [4096][1024]

  wtrans_kernel<<<dim3(32, 32, 4), 256, 0, stream>>>(wq, wk, wv, wo, WT);
  proj_kernel<<<dim3(768), 256, 0, stream>>>(q, k, v, WT, Qh, Kh, Vt);
  attn_kernel<<<dim3(512), 512, 0, stream>>>(Qh, Kh, Vt, Ob);
  outproj_kernel<<<dim3(512), 256, 0, stream>>>(Ob, WT + (size_t)3 * 1024 * 1024, out);
}

// Round 12
// 121.596 us; speedup vs baseline: 1.3249x; 1.0569x over previous
//
#include <hip/hip_runtime.h>
#include <hip/hip_bf16.h>

// B=2, S=2048, H=16, D=64, D_MODEL=1024, M=B*S=4096
// ws layout (bytes):
//   WT  @ 0MB  : [4][1024][1024] bf16 (w_q^T, w_k^T, w_v^T, w_o^T)  8MB
//   Qh  @ 32MB : [32][2048][64]  bf16 (scaled by 0.125*log2e)       8MB
//   Kh  @ 40MB : [32][2048][64]  bf16                               8MB
//   Vt  @ 48MB : [32][64][2048]  bf16 (per-head transposed V)       8MB
//   Ob  @ 56MB : [4096][1024]    bf16 (attention output)            8MB

using bf16x8 = __attribute__((ext_vector_type(8))) short;
using f32x4  = __attribute__((ext_vector_type(4))) float;
using u32x4  = __attribute__((ext_vector_type(4))) unsigned;
typedef unsigned short u16;
using u16x4 = __attribute__((ext_vector_type(4))) u16;
using u16x8 = __attribute__((ext_vector_type(8))) u16;

#define GLDS16(g, l) __builtin_amdgcn_global_load_lds( \
    (const __attribute__((address_space(1))) void*)(g), \
    (__attribute__((address_space(3))) void*)(l), 16, 0, 0)

#if __has_builtin(__builtin_amdgcn_exp2f)
#define EXP2(x) __builtin_amdgcn_exp2f(x)
#else
#define EXP2(x) exp2f(x)
#endif

// Raw s_barrier is IntrNoMem: pair it with compiler memory fences so LDS
// reads/writes cannot be moved across it at compile time.
__device__ __forceinline__ void block_sync() {
  __builtin_amdgcn_sched_barrier(0);
  asm volatile("" ::: "memory");
  __builtin_amdgcn_s_barrier();
  asm volatile("" ::: "memory");
  __builtin_amdgcn_sched_barrier(0);
}

__device__ __forceinline__ u16 f2bf(float f) {
  unsigned u = __builtin_bit_cast(unsigned, f);
  u += 0x7fffu + ((u >> 16) & 1u);
  return (u16)(u >> 16);
}

// packed f32->bf16 RNE (no builtin on gfx950; T12 primitive)
__device__ __forceinline__ unsigned cvt_pk_bf16(float lo, float hi) {
  unsigned r;
  asm("v_cvt_pk_bf16_f32 %0, %1, %2" : "=v"(r) : "v"(lo), "v"(hi));
  return r;
}

__device__ __forceinline__ float fmax3(float a, float b, float c) {
  return fmaxf(fmaxf(a, b), c);  // clang fuses to v_max3_f32
}

// ---------- kernel 1: weight transpose+convert: WT[z][n][k] = bf16(w_z[k][n]) ----------
__global__ __launch_bounds__(256) void wtrans_kernel(
    const float* __restrict__ wq, const float* __restrict__ wk,
    const float* __restrict__ wv, const float* __restrict__ wo,
    u16* __restrict__ dst) {
  __shared__ float t[32][33];
  const int z = blockIdx.z;
  const float* src = (z == 0) ? wq : (z == 1) ? wk : (z == 2) ? wv : wo;
  u16* d = dst + (size_t)z * 1024 * 1024;
  const int tx = threadIdx.x & 31, ty = threadIdx.x >> 5;
  const int bx = blockIdx.x * 32, by = blockIdx.y * 32;
#pragma unroll
  for (int j = 0; j < 4; j++)
    t[ty + j * 8][tx] = src[(size_t)(by + ty + j * 8) * 1024 + bx + tx];
  __syncthreads();
#pragma unroll
  for (int j = 0; j < 4; j++)
    d[(size_t)(bx + ty + j * 8) * 1024 + by + tx] = f2bf(t[tx][ty + j * 8]);
}

// ---------- kernel 2: fused QKV projections (pipelined, XCD-chunked) ----------
// 768 blocks 1-D; xcd=id&7 owns y-panels [4*xcd,4*xcd+4) x all 8 bcols per z
// -> each fp32 A-panel read by ONE XCD (8 bx blocks share it via L2).
// Pipeline (T14): tile k+1's A-reg loads + B glds issued BEFORE tile k's MFMA,
// drained by counted vmcnt(12) (= A(8)+B(4) of tile k); next-tile loads stay
// in flight across the MFMA phase. ldsB double-buffered; 48KB -> 3 blocks/CU,
// 768-block grid exactly resident.
__global__ __launch_bounds__(256, 3) void proj_kernel(
    const float* __restrict__ qf, const float* __restrict__ kf,
    const float* __restrict__ vf, const u16* __restrict__ WT,
    u16* __restrict__ Qh, u16* __restrict__ Kh, u16* __restrict__ Vt) {
  __shared__ u16 lds[24576];          // [0,8192): A; [8192,16384): B0; [16384,24576): B1
  const int id = blockIdx.x;
  const int xcd = id & 7, l = id >> 3;      // l in [0,96)
  const int z = l >> 5, rem = l & 31;       // 32 blocks per XCD per z
  const int by = xcd * 4 + (rem >> 3);      // 4 y-panels per XCD
  const int bx = rem & 7;
  const int arow0 = by * 128, bcol0 = bx * 128;
  const float* A = (z == 0) ? qf : (z == 1) ? kf : vf;
  const u16* Bw = WT + (size_t)z * 1024 * 1024;

  const int tid = threadIdx.x;
  const int lane = tid & 63, wave = tid >> 6;
  const int lr = lane & 15, lg = lane >> 4;
  const int wr = (wave >> 1) * 64, wc = (wave & 1) * 64;
  const int ar = tid >> 3, ac = tid & 7;    // A/B stage: row base, chunk
  f32x4 acc[4][4] = {};

  f32x4 fa[4][2];    // in-flight A fp32 regs (8 loads/tile)
  u32x4 w[4];        // packed bf16 A (consumed by ds_write before barrier)

  auto LOADA = [&](int kt) {
#pragma unroll
    for (int i = 0; i < 4; i++) {
      const float* ap = A + (size_t)(arow0 + i * 32 + ar) * 1024 + kt + ac * 8;
      fa[i][0] = *(const f32x4*)ap;
      fa[i][1] = *(const f32x4*)(ap + 4);
    }
  };
  auto GLDSB = [&](int kt, int nb) {
    u16* bd = lds + 8192 + nb * 8192;
#pragma unroll
    for (int i = 0; i < 4; i++) {
      int o = (i * 256 + tid) * 8;
      int row = o >> 6, ch = (o >> 3) & 7;
      int sc = (ch ^ (row & 7)) << 3;
      GLDS16(Bw + (size_t)(bcol0 + row) * 1024 + kt + sc, bd + o);
    }
  };
  auto CVT = [&]() {
#pragma unroll
    for (int i = 0; i < 4; i++) {
      u32x4 v = {cvt_pk_bf16(fa[i][0][0], fa[i][0][1]),
                 cvt_pk_bf16(fa[i][0][2], fa[i][0][3]),
                 cvt_pk_bf16(fa[i][1][0], fa[i][1][1]),
                 cvt_pk_bf16(fa[i][1][2], fa[i][1][3])};
      w[i] = v;
    }
  };
  auto WRITEA = [&]() {
#pragma unroll
    for (int i = 0; i < 4; i++) {
      int row = i * 32 + ar;
      *(u32x4*)&lds[row * 64 + ((ac ^ (row & 7)) << 3)] = w[i];
    }
  };
  auto MFMAK = [&](int cb) {
    const u16* Bb = lds + 8192 + cb * 8192;
#pragma unroll
    for (int kk = 0; kk < 2; kk++) {
      bf16x8 af[4], bfr[4];
      const int ke = kk * 32 + lg * 8;
#pragma unroll
      for (int m = 0; m < 4; m++) {
        int row = wr + m * 16 + lr;
        af[m] = *(const bf16x8*)&lds[row * 64 + (ke ^ ((row & 7) << 3))];
      }
#pragma unroll
      for (int n = 0; n < 4; n++) {
        int row = wc + n * 16 + lr;
        bfr[n] = *(const bf16x8*)&Bb[row * 64 + (ke ^ ((row & 7) << 3))];
      }
#pragma unroll
      for (int m = 0; m < 4; m++)
#pragma unroll
        for (int n = 0; n < 4; n++)
          acc[m][n] = __builtin_amdgcn_mfma_f32_16x16x32_bf16(af[m], bfr[n],
                                                              acc[m][n], 0, 0, 0);
    }
  };

#define PSTEP(KT, CB, MORE)                                                  \
  do {                                                                       \
    CVT();                                                                   \
    if (MORE) { LOADA((KT) + 64); GLDSB((KT) + 64, (CB) ^ 1); }              \
    WRITEA();                                                                \
    if (MORE)                                                                \
      asm volatile("s_waitcnt vmcnt(12) lgkmcnt(0)" ::: "memory");           \
    else                                                                     \
      asm volatile("s_waitcnt vmcnt(0) lgkmcnt(0)" ::: "memory");            \
    block_sync();                                                            \
    MFMAK(CB);                                                               \
    block_sync();                                                            \
  } while (0)

  LOADA(0);
  GLDSB(0, 0);
  for (int kt = 0; kt < 896; kt += 128) {   // tiles 0..13 (7 pairs)
    PSTEP(kt, 0, true);
    PSTEP(kt + 64, 1, true);
  }
  PSTEP(896, 0, true);   // tile 14, issues tile 15 -> buf 1
  PSTEP(960, 1, false);  // tile 15, final drain
#undef PSTEP

  if (z == 2) {
    // V: transpose through LDS -> Vt[(b*16+h)*64+d][s]
    u16* T = lds;  // [128 c][128 s], swizzled rows (32KB of the 48KB)
    __syncthreads();
#pragma unroll
    for (int m = 0; m < 4; m++)
#pragma unroll
      for (int n = 0; n < 4; n++)
#pragma unroll
        for (int r = 0; r < 4; r++) {
          int sl = wr + m * 16 + lg * 4 + r;
          int cl = wc + n * 16 + lr;
          T[cl * 128 + (sl ^ ((cl & 7) << 3))] = f2bf(acc[m][n][r]);
        }
    __syncthreads();
    const int t = threadIdx.x;
    const int cl = t >> 1, s0 = (t & 1) * 64;
    const int gc = bcol0 + cl;
    const size_t vrow = ((size_t)(arow0 >> 11) * 16 + (gc >> 6)) * 64 + (gc & 63);
#pragma unroll
    for (int j = 0; j < 8; j++) {
      int sl = s0 + j * 8;
      u16x8 vv = *(const u16x8*)&T[cl * 128 + (sl ^ ((cl & 7) << 3))];
      *(u16x8*)&Vt[vrow * 2048 + (size_t)((arow0 & 2047) + sl)] = vv;
    }
  } else {
    const float scale = (z == 0) ? 0.18033688f : 1.0f;  // 0.125 * log2(e)
    u16* dst = (z == 0) ? Qh : Kh;
#pragma unroll
    for (int m = 0; m < 4; m++)
#pragma unroll
      for (int n = 0; n < 4; n++)
#pragma unroll
        for (int r = 0; r < 4; r++) {
          int gr = arow0 + wr + m * 16 + lg * 4 + r;
          int gc = bcol0 + wc + n * 16 + lr;
          size_t idx = (((size_t)(gr >> 11) * 16 + (gc >> 6)) * 2048 +
                        (gr & 2047)) * 64 + (gc & 63);
          dst[idx] = f2bf(acc[m][n][r] * scale);
        }
  }
}

// ---------- kernel 3: flash attention (swapped QK^T, P in registers) ----------
// 512 blocks (XCD-swizzled) x 8 waves, 128 q-rows per block, 16 per wave.
// Quad-buffered K/V (64KB LDS), 2-deep prefetch, steady vmcnt(6);
// launch_bounds(512,4) -> 2 blocks/CU = 16 waves/CU, grid exactly resident.
// S^T = mfma(K-frag, Q-frag): lane owns q = lane&15; K rows fed through
// permutation κ(n,a)=32(n>>1)+8(a>>2)+4(n&1)+(a&3) so the lane's 16 keys are
// exactly the PV A-fragment sets {8*lg..+7} u {32+8*lg..+7} -> zero exchange.
// K bank swizzle h(kr)=(kr&3)|(((kr>>3)&1)<<2): bijective on bank-groups for
// every 8 consecutive lanes.
__global__ __launch_bounds__(512, 4) void attn_kernel(
    const u16* __restrict__ Qh, const u16* __restrict__ Kh,
    const u16* __restrict__ Vt, u16* __restrict__ Ob) {
  __shared__ u16 kt[4][64 * 64];  // K tiles [key][d], h-swizzled rows
  __shared__ u16 vt[4][64 * 64];  // V^T tiles [d][s], xor-swizzled rows
  const int tid = threadIdx.x;
  const int lane = tid & 63, wave = tid >> 6;
  const int lr = lane & 15, lg = lane >> 4;
  // bijective XCD swizzle (512 % 8 == 0): each XCD owns 4 complete bh's
  const int id = blockIdx.x;
  const int swz = (id & 7) * 64 + (id >> 3);
  const int bh = swz >> 4;
  const int q0 = (swz & 15) * 128;
  const u16* Qb = Qh + ((size_t)bh * 2048 + q0) * 64;
  const u16* Kb = Kh + (size_t)bh * 2048 * 64;
  const u16* Vb = Vt + (size_t)bh * 64 * 2048;

  // Q fragment (B-operand of swapped QK^T); wave owns q-rows [wave*16, +16)
  bf16x8 aq[2];
#pragma unroll
  for (int kk = 0; kk < 2; kk++)
    aq[kk] = *(const bf16x8*)(Qb + (wave * 16 + lr) * 64 + kk * 32 + lg * 8);

  // K A-operand LDS offsets: perm κ, swizzle h (h depends only on lr)
  const int hsw = (lr & 3) | (((lr >> 2) & 1) << 2);
  int koff[2][4];
#pragma unroll
  for (int n = 0; n < 4; n++) {
    int kr = 32 * (n >> 1) + 8 * (lr >> 2) + 4 * (n & 1) + (lr & 3);
#pragma unroll
    for (int kk = 0; kk < 2; kk++)
      koff[kk][n] = kr * 64 + ((kk * 32 + lg * 8) ^ (hsw << 3));
  }
  // V B-operand LDS offsets
  int voff[2][4];
#pragma unroll
  for (int n = 0; n < 4; n++) {
    int d = n * 16 + lr;
#pragma unroll
    for (int ks = 0; ks < 2; ks++)
      voff[ks][n] = d * 64 + ((ks * 32 + lg * 8) ^ ((d & 7) << 3));
  }

  // staging: 512 threads cover one 64x64 K tile + one 64x64 V tile,
  // 1 chunk of 16B each; row = tid>>3, ch = tid&7
  const int o0 = tid * 8;
  const int srow = tid >> 3, sch = tid & 7;
  const int hk = (srow & 3) | (((srow >> 3) & 1) << 2);
  const u16* kg = Kb + (size_t)srow * 64 + ((sch ^ hk) << 3);
  const u16* vg = Vb + (size_t)srow * 2048 + ((sch ^ (srow & 7)) << 3);

  f32x4 oacc[4] = {};
  float mrun = -1e30f, lrun = 0.f;

  auto STAGE = [&](int t, int b) {  // b literal at call site; 2 insts/thread
    GLDS16(kg + (size_t)t * 4096, &kt[0][0] + b * 4096 + o0);
    GLDS16(vg + t * 64, &vt[0][0] + b * 4096 + o0);
  };

  auto COMPUTE = [&](int cur) {  // cur literal at call site
    // S^T tile: sacc[n][r] = S[key κ(n, lg*4+r)][q=lr] (log2 domain)
    f32x4 sacc[4] = {};
    __builtin_amdgcn_s_setprio(1);
#pragma unroll
    for (int kk = 0; kk < 2; kk++) {
#pragma unroll
      for (int n = 0; n < 4; n++) {
        bf16x8 ka = *(const bf16x8*)&kt[cur][koff[kk][n]];
        sacc[n] = __builtin_amdgcn_mfma_f32_16x16x32_bf16(ka, aq[kk],
                                                          sacc[n], 0, 0, 0);
      }
    }
    __builtin_amdgcn_s_setprio(0);
    // row max: 7 max3 + 1 fmax in-lane, then 2 cross-lane steps
    float t0 = fmax3(sacc[0][0], sacc[0][1], sacc[0][2]);
    float t1 = fmax3(sacc[0][3], sacc[1][0], sacc[1][1]);
    float t2 = fmax3(sacc[1][2], sacc[1][3], sacc[2][0]);
    float t3 = fmax3(sacc[2][1], sacc[2][2], sacc[2][3]);
    float t4 = fmax3(sacc[3][0], sacc[3][1], sacc[3][2]);
    float mx = fmaxf(fmax3(t0, t1, t2), fmax3(t3, t4, sacc[3][3]));
    mx = fmaxf(mx, __shfl_xor(mx, 16));
    mx = fmaxf(mx, __shfl_xor(mx, 32));
    float mnew = fmaxf(mrun, mx);
    // defer-max (T13): skip rescale when growth <= 8 (log2 domain -> p <= 256)
    if (__all(mx - mrun <= 8.0f)) {
      mnew = mrun;
    } else {
      float corr = EXP2(mrun - mnew);
      mrun = mnew;
      lrun *= corr;
      float cr[4];
#pragma unroll
      for (int r = 0; r < 4; r++) cr[r] = __shfl(corr, lg * 4 + r);
#pragma unroll
      for (int n = 0; n < 4; n++)
#pragma unroll
        for (int r = 0; r < 4; r++) oacc[n][r] *= cr[r];
    }
    // p = exp2(s - m), in place; row-sum
    float psum = 0.f;
#pragma unroll
    for (int n = 0; n < 4; n++)
#pragma unroll
      for (int r = 0; r < 4; r++) {
        float p = EXP2(sacc[n][r] - mnew);
        sacc[n][r] = p;
        psum += p;
      }
    psum += __shfl_xor(psum, 16);
    psum += __shfl_xor(psum, 32);
    lrun += psum;
    // pack P into PV A-fragments via v_cvt_pk_bf16_f32
    u32x4 w0 = {cvt_pk_bf16(sacc[0][0], sacc[0][1]),
                cvt_pk_bf16(sacc[0][2], sacc[0][3]),
                cvt_pk_bf16(sacc[1][0], sacc[1][1]),
                cvt_pk_bf16(sacc[1][2], sacc[1][3])};
    u32x4 w1 = {cvt_pk_bf16(sacc[2][0], sacc[2][1]),
                cvt_pk_bf16(sacc[2][2], sacc[2][3]),
                cvt_pk_bf16(sacc[3][0], sacc[3][1]),
                cvt_pk_bf16(sacc[3][2], sacc[3][3])};
    bf16x8 pa0 = __builtin_bit_cast(bf16x8, w0);
    bf16x8 pa1 = __builtin_bit_cast(bf16x8, w1);
    // O += P V
    __builtin_amdgcn_s_setprio(1);
#pragma unroll
    for (int ks = 0; ks < 2; ks++) {
      bf16x8 ap = ks ? pa1 : pa0;
      bf16x8 bv[4];
#pragma unroll
      for (int n = 0; n < 4; n++)
        bv[n] = *(const bf16x8*)&vt[cur][voff[ks][n]];
#pragma unroll
      for (int n = 0; n < 4; n++)
        oacc[n] = __builtin_amdgcn_mfma_f32_16x16x32_bf16(ap, bv[n],
                                                          oacc[n], 0, 0, 0);
    }
    __builtin_amdgcn_s_setprio(0);
  };

#define VMC6 asm volatile("s_waitcnt vmcnt(6)" ::: "memory")
#define VMC4 asm volatile("s_waitcnt vmcnt(4)" ::: "memory")
#define VMC2 asm volatile("s_waitcnt vmcnt(2)" ::: "memory")
#define VMC0 asm volatile("s_waitcnt vmcnt(0)" ::: "memory")
  STAGE(0, 0); STAGE(1, 1); STAGE(2, 2);
  // quad-buffered, 2 tiles in flight; unrolled x4 so buf indices are literals
  for (int t = 0; t < 28; t += 4) {
    STAGE(t + 3, 3); VMC6; block_sync(); COMPUTE(0); block_sync();
    STAGE(t + 4, 0); VMC6; block_sync(); COMPUTE(1); block_sync();
    STAGE(t + 5, 1); VMC6; block_sync(); COMPUTE(2); block_sync();
    STAGE(t + 6, 2); VMC6; block_sync(); COMPUTE(3); block_sync();
  }
  // staged 0..30, computed 0..27
  STAGE(31, 3); VMC6; block_sync(); COMPUTE(0); block_sync();  // tile 28
  VMC4; block_sync(); COMPUTE(1); block_sync();                // tile 29
  VMC2; block_sync(); COMPUTE(2); block_sync();                // tile 30
  VMC0; block_sync(); COMPUTE(3);                              // tile 31
#undef VMC6
#undef VMC4
#undef VMC2
#undef VMC0

  // epilogue: normalize (inv lives at q=lr; oacc rows are q=lg*4+r)
  const int b = bh >> 4, h = bh & 15;
  float inv = 1.0f / lrun;
  float ivr[4];
#pragma unroll
  for (int r = 0; r < 4; r++) ivr[r] = __shfl(inv, lg * 4 + r);
#pragma unroll
  for (int r = 0; r < 4; r++) {
    int qrow = q0 + wave * 16 + lg * 4 + r;
#pragma unroll
    for (int n = 0; n < 4; n++) {
      int d = n * 16 + lr;
      Ob[((size_t)b * 2048 + qrow) * 1024 + h * 64 + d] = f2bf(oacc[n][r] * ivr[r]);
    }
  }
}

// ---------- kernel 4: output projection (128x64 tile, XCD-chunked 512 blocks) ----------
__global__ __launch_bounds__(256) void outproj_kernel(
    const u16* __restrict__ Ob, const u16* __restrict__ WoT,
    float* __restrict__ out) {
  __shared__ u16 ldsA[128 * 64];  // 16KB, swizzled rows
  __shared__ u16 ldsB[64 * 64];   //  8KB, swizzled rows
  const int tid = threadIdx.x;
  const int lane = tid & 63, wave = tid >> 6;
  const int lr = lane & 15, lg = lane >> 4;
  const int wr = (wave >> 1) * 64;  // M offset (0/64)
  const int wc = (wave & 1) * 32;   // N offset (0/32)
  // XCD-chunked: xcd owns 4 y-panels x all 16 x -> each A panel one XCD
  const int id = blockIdx.x;
  const int xcd = id & 7, l = id >> 3;   // l in [0,64)
  const int by = xcd * 4 + (l >> 4);     // 0..31
  const int bx = l & 15;                 // 0..15
  const int arow0 = by * 128, bcol0 = bx * 64;
  f32x4 acc[4][2] = {};
  for (int kt = 0; kt < 1024; kt += 64) {
#pragma unroll
    for (int i = 0; i < 4; i++) {
      int o = (i * 256 + tid) * 8;
      int row = o >> 6, ch = (o >> 3) & 7;
      int sc = (ch ^ (row & 7)) << 3;
      GLDS16(Ob + (size_t)(arow0 + row) * 1024 + kt + sc, &ldsA[o]);
    }
#pragma unroll
    for (int i = 0; i < 2; i++) {
      int o = (i * 256 + tid) * 8;
      int row = o >> 6, ch = (o >> 3) & 7;
      int sc = (ch ^ (row & 7)) << 3;
      GLDS16(WoT + (size_t)(bcol0 + row) * 1024 + kt + sc, &ldsB[o]);
    }
    __syncthreads();
#pragma unroll
    for (int kk = 0; kk < 2; kk++) {
      const int ke = kk * 32 + lg * 8;
      bf16x8 af[4], bfr[2];
#pragma unroll
      for (int m = 0; m < 4; m++) {
        int row = wr + m * 16 + lr;
        af[m] = *(const bf16x8*)&ldsA[row * 64 + (ke ^ ((row & 7) << 3))];
      }
#pragma unroll
      for (int n = 0; n < 2; n++) {
        int row = wc + n * 16 + lr;
        bfr[n] = *(const bf16x8*)&ldsB[row * 64 + (ke ^ ((row & 7) << 3))];
      }
#pragma unroll
      for (int m = 0; m < 4; m++)
#pragma unroll
        for (int n = 0; n < 2; n++)
          acc[m][n] = __builtin_amdgcn_mfma_f32_16x16x32_bf16(af[m], bfr[n],
                                                              acc[m][n], 0, 0, 0);
    }
    __syncthreads();
  }
#pragma unroll
  for (int m = 0; m < 4; m++)
#pragma unroll
    for (int n = 0; n < 2; n++)
#pragma unroll
      for (int r = 0; r < 4; r++) {
        int gr = arow0 + wr + m * 16 + lg * 4 + r;
        int gc = bcol0 + wc + n * 16 + lr;
        out[(size_t)gr * 1024 + gc] = acc[m][n][r];
      }
}

extern "C" void kernel_launch(void* const* d_in, const int* in_sizes, int n_in,
                              void* d_out, int out_size, void* d_ws, size_t ws_size,
                              hipStream_t stream) {
  const float* q  = (const float*)d_in[0];
  const float* k  = (const float*)d_in[1];
  const float* v  = (const float*)d_in[2];
  const float* wq = (const float*)d_in[3];
  const float* wk = (const float*)d_in[4];
  const float* wv = (const float*)d_in[5];
  const float* wo = (const float*)d_in[6];
  float* out = (float*)d_out;
  char* ws = (char*)d_ws;

  u16* WT = (u16*)ws;                                    // [4][1024][1024]
  u16* Qh = (u16*)(ws + (size_t)32 * 1024 * 1024);       // [32][2048][64]
  u16* Kh = (u16*)(ws + (size_t)40 * 1024 * 1024);       // [32][2048][64]
  u16* Vt = (u16*)(ws + (size_t)48 * 1024 * 1024);       // [32][64][2048]
  u16* Ob = (u16*)(ws + (size_t)56 * 1024 * 1024);       // [4096][1024]

  wtrans_kernel<<<dim3(32, 32, 4), 256, 0, stream>>>(wq, wk, wv, wo, WT);
  proj_kernel<<<dim3(768), 256, 0, stream>>>(q, k, v, WT, Qh, Kh, Vt);
  attn_kernel<<<dim3(512), 512, 0, stream>>>(Qh, Kh, Vt, Ob);
  outproj_kernel<<<dim3(512), 256, 0, stream>>>(Ob, WT + (size_t)3 * 1024 * 1024, out);
}